// Round 9
// baseline (1482.991 us; speedup 1.0000x reference)
//
#include <hip/hip_runtime.h>
#include <math.h>
#include <stdint.h>
#include <limits.h>

#define NN 100000
#define NE 1600000
#define HH 64
#define THF 0.7f
#define ATTTH 0.2f
#define EPSF 1e-5f
#define SCAN_B ((NN + 255) / 256)   // 391
#define EM2CAP 1000000
#define NBE 2048
#define NHTOT ((size_t)NN * 64)
#define NB_ROW4C (NN / 4)
#define NTILE (NN / 32)             // 3125

typedef unsigned long long u64;

// wave-uniform broadcast: v_readlane_b32 (scalar pipe) instead of ds_bpermute.
__device__ inline int bcast_i(int v, int l) {
    return __builtin_amdgcn_readlane(v, l);
}
__device__ inline unsigned bcast_u(unsigned v, int l) {
    return (unsigned)__builtin_amdgcn_readlane((int)v, l);
}
__device__ inline float bcast_f(float v, int l) {
    return __int_as_float(__builtin_amdgcn_readlane(__float_as_int(v), l));
}

// ---------------- setup ----------------

// ONE packed atomic per edge: low16 = all-count, high16 = mask-count.
__global__ void hist_k(const int* __restrict__ dst, const int* __restrict__ mask,
                       int* __restrict__ cntp, int* __restrict__ rk) {
    int e = blockIdx.x * 256 + threadIdx.x;
    if (e >= NE) return;
    int d = dst[e];
    int inc = 1 | ((mask[e] & 1) << 16);
    rk[e] = atomicAdd(&cntp[d], inc);
}

// dual scan over packed counts with fused degree-inverse computation
__global__ void scan1d_k(const int* __restrict__ cntp,
                         int* __restrict__ rp1, int* __restrict__ rp2,
                         int* __restrict__ bsum,
                         float* __restrict__ dis1, float* __restrict__ d21,
                         float* __restrict__ dis2m, float* __restrict__ d22) {
    __shared__ int ls[256];
    int half = (blockIdx.x >= SCAN_B) ? 1 : 0;
    int blk = blockIdx.x - half * SCAN_B;
    int* rp = half ? rp2 : rp1;
    int i = blk * 256 + threadIdx.x;
    int p = (i < NN) ? cntp[i] : 0;
    int v = half ? (p >> 16) : (p & 0xFFFF);
    if (i < NN) {
        float dg = (float)(v + 1);
        float is = 1.0f / sqrtf(dg);
        float iv = 1.0f / dg;
        if (half) { dis2m[i] = is; d22[i] = iv; }
        else      { dis1[i] = is;  d21[i] = iv; }
    }
    ls[threadIdx.x] = v;
    __syncthreads();
    for (int off = 1; off < 256; off <<= 1) {
        int t = (threadIdx.x >= off) ? ls[threadIdx.x - off] : 0;
        __syncthreads();
        ls[threadIdx.x] += t;
        __syncthreads();
    }
    if (i < NN) rp[i] = ls[threadIdx.x] - v;
    if (threadIdx.x == 255) bsum[blockIdx.x] = ls[255];
}

__global__ __launch_bounds__(512) void scan2d_k(int* __restrict__ bsum,
                                                int* __restrict__ rp1,
                                                int* __restrict__ rp2) {
    __shared__ int ls[512];
    int i = threadIdx.x;
    for (int s = 0; s < 2; s++) {
        int v = (i < SCAN_B) ? bsum[s * SCAN_B + i] : 0;
        ls[i] = v;
        __syncthreads();
        for (int off = 1; off < 512; off <<= 1) {
            int t = (i >= off) ? ls[i - off] : 0;
            __syncthreads();
            ls[i] += t;
            __syncthreads();
        }
        if (i < SCAN_B) bsum[s * SCAN_B + i] = ls[i] - v;
        if (i == SCAN_B - 1) { if (s == 0) rp1[NN] = ls[i]; else rp2[NN] = ls[i]; }
        __syncthreads();
    }
}

__global__ void scan3d_k(int* __restrict__ rp1, int* __restrict__ rp2,
                         const int* __restrict__ bsum) {
    int half = (blockIdx.x >= SCAN_B) ? 1 : 0;
    int blk = blockIdx.x - half * SCAN_B;
    int* rp = half ? rp2 : rp1;
    int i = blk * 256 + threadIdx.x;
    if (i < NN) rp[i] += bsum[blockIdx.x];
}

// emA[p] = (src<<1)|mask (all edges); emB[p] = src (masked edges only)
__global__ void csr_fill_k(const int* __restrict__ src, const int* __restrict__ dst,
                           const int* __restrict__ mask, const int* __restrict__ rk,
                           const int* __restrict__ rp1, const int* __restrict__ rp2,
                           int* __restrict__ emA, int* __restrict__ emB) {
    int e = blockIdx.x * 256 + threadIdx.x;
    if (e >= NE) return;
    int s = src[e], d = dst[e];
    int mk = mask[e] & 1;
    int r = rk[e];
    emA[rp1[d] + (r & 0xFFFF)] = (s << 1) | mk;
    if (mk) emB[rp2[d] + (r >> 16)] = s;
}

// sort int segment ascending (keys may duplicate; value IS the key)
__device__ void seg_sort_node(int* __restrict__ em, int beg, int end,
                              int* skey, int lane) {
    int L = end - beg;
    if (L <= 1) return;
    if (L <= 64) {
        int k = (lane < L) ? em[beg + lane] : INT_MAX;
        int rank = 0;
#pragma unroll 8
        for (int r = 0; r < L; r++) {
            int kr = bcast_i(k, r);
            rank += (kr < k || (kr == k && r < lane)) ? 1 : 0;
        }
        if (lane < L) em[beg + rank] = k;
    } else if (L <= 512) {
        for (int i = lane; i < L; i += 64) skey[i] = em[beg + i];
        for (int it = 0; it < L; it++) {
            int par = it & 1;
            for (int p = par + 2 * lane; p + 1 < L; p += 128) {
                int ka = skey[p], kb = skey[p + 1];
                if (kb < ka) { skey[p] = kb; skey[p + 1] = ka; }
            }
        }
        for (int i = lane; i < L; i += 64) em[beg + i] = skey[i];
    }
}

__global__ __launch_bounds__(256) void seg_sort2_k(int* __restrict__ emA,
                                                   const int* __restrict__ rp1,
                                                   int* __restrict__ emB,
                                                   const int* __restrict__ rp2) {
    __shared__ int skey[4][512];
    int tid = threadIdx.x, lane = tid & 63, w = tid >> 6;
    int bid = blockIdx.x;
    if (bid < NB_ROW4C) {
        int n = bid * 4 + w;
        seg_sort_node(emA, rp1[n], rp1[n + 1], skey[w], lane);
    } else {
        int n = (bid - NB_ROW4C) * 4 + w;
        seg_sort_node(emB, rp2[n], rp2[n + 1], skey[w], lane);
    }
}

// ---------------- GEMM (float input, layer 0 only) ----------------

__global__ __launch_bounds__(256) void gemm_k(const float* __restrict__ in,
                                              const float* __restrict__ W,
                                              float* __restrict__ xw) {
    __shared__ float sW[64 * 64];
    __shared__ float sx[32 * 65];
    int tid = threadIdx.x;
    const float4* W4 = (const float4*)W;
    float4* sW4 = (float4*)sW;
    for (int i = tid; i < 1024; i += 256) sW4[i] = W4[i];
    const float* inb = in + (size_t)blockIdx.x * 2048;
    for (int i = tid; i < 2048; i += 256) sx[(i >> 6) * 65 + (i & 63)] = inb[i];
    __syncthreads();
    int cg = tid & 15, rr = tid >> 4;
    float a0 = 0, a1 = 0, a2 = 0, a3 = 0, c0 = 0, c1 = 0, c2 = 0, c3 = 0;
#pragma unroll
    for (int k = 0; k < 64; k++) {
        float4 wv = *(const float4*)&sW[k * 64 + cg * 4];
        float xa = sx[rr * 65 + k];
        float xb = sx[(rr + 16) * 65 + k];
        a0 += xa * wv.x; a1 += xa * wv.y; a2 += xa * wv.z; a3 += xa * wv.w;
        c0 += xb * wv.x; c1 += xb * wv.y; c2 += xb * wv.z; c3 += xb * wv.w;
    }
    size_t r0 = (size_t)(blockIdx.x * 32 + rr) * 64 + cg * 4;
    size_t r1 = (size_t)(blockIdx.x * 32 + rr + 16) * 64 + cg * 4;
    *(float4*)&xw[r0] = make_float4(a0, a1, a2, a3);
    *(float4*)&xw[r1] = make_float4(c0, c1, c2, c3);
}

// ---------------- float gather (fallback L0 only) ----------------

__global__ __launch_bounds__(256) void gather_stats_k(const float* __restrict__ xw,
                                                      const int* __restrict__ em,
                                                      int shift,
                                                      const float* __restrict__ dis,
                                                      const int* __restrict__ rp,
                                                      const float* __restrict__ d2i,
                                                      const float* __restrict__ bias,
                                                      float* __restrict__ out,
                                                      double* __restrict__ part) {
    int tid = threadIdx.x, lane = tid & 63, w = tid >> 6;
    double ps = 0.0, pq = 0.0;
    for (int n = blockIdx.x * 4 + w; n < NN; n += NBE * 4) {
        int beg = rp[n], end = rp[n + 1];
        float disn = dis[n];
        float self = d2i[n] * xw[(size_t)n * 64 + lane] + bias[lane];
        float acc = 0.0f;
        for (int base = beg; base < end; base += 64) {
            int cnt = min(64, end - base);
            int m = 0; float nl = 0.0f;
            if (base + lane < end) {
                m = em[base + lane];
                nl = dis[m >> shift] * disn;
            }
            int j = 0;
            for (; j + 8 <= cnt; j += 8) {
#pragma unroll
                for (int u = 0; u < 8; u++) {
                    int s = bcast_i(m, j + u) >> shift;
                    float nv = bcast_f(nl, j + u);
                    acc += nv * xw[(size_t)s * 64 + lane];
                }
            }
            for (; j < cnt; j++) {
                int s = bcast_i(m, j) >> shift;
                float nv = bcast_f(nl, j);
                acc += nv * xw[(size_t)s * 64 + lane];
            }
        }
        float o = acc + self;
        out[(size_t)n * 64 + lane] = o;
        ps += (double)o;
        pq += (double)o * (double)o;
    }
    __shared__ double ls[4][64], lq[4][64];
    ls[w][lane] = ps; lq[w][lane] = pq;
    __syncthreads();
    if (tid < 64) {
        double a = ls[0][tid] + ls[1][tid] + ls[2][tid] + ls[3][tid];
        double b = lq[0][tid] + lq[1][tid] + lq[2][tid] + lq[3][tid];
        part[(size_t)blockIdx.x * 128 + tid] = a;
        part[(size_t)blockIdx.x * 128 + 64 + tid] = b;
    }
}

// shared L0: one emA traversal -> enc1 + enc2 first aggregation (float rows)
__global__ __launch_bounds__(256) void sharedL0_k(const float* __restrict__ xw,
                                                  const int* __restrict__ em,
                                                  const int* __restrict__ rp,
                                                  const float* __restrict__ dis1,
                                                  const float* __restrict__ dis2m,
                                                  const float* __restrict__ d21,
                                                  const float* __restrict__ d22,
                                                  const float* __restrict__ bias,
                                                  float* __restrict__ o1,
                                                  float* __restrict__ o2,
                                                  double* __restrict__ part) {
    int tid = threadIdx.x, lane = tid & 63, w = tid >> 6;
    double sA = 0.0, qA = 0.0, sB = 0.0, qB = 0.0;
    for (int n = blockIdx.x * 4 + w; n < NN; n += NBE * 4) {
        int beg = rp[n], end = rp[n + 1];
        float disn1 = dis1[n], disn2 = dis2m[n];
        float xv = xw[(size_t)n * 64 + lane];
        float self1 = d21[n] * xv + bias[lane];
        float self2 = d22[n] * xv + bias[lane];
        float acc1 = 0.0f, acc2 = 0.0f;
        for (int base = beg; base < end; base += 64) {
            int cnt = min(64, end - base);
            int m = 0; float nl1 = 0.0f, nl2 = 0.0f;
            if (base + lane < end) {
                m = em[base + lane];
                int s = m >> 1;
                nl1 = dis1[s] * disn1;
                nl2 = dis2m[s] * disn2;
            }
            int j = 0;
            for (; j + 8 <= cnt; j += 8) {
#pragma unroll
                for (int u = 0; u < 8; u++) {
                    int key = bcast_i(m, j + u);
                    int s = key >> 1;
                    float n1 = bcast_f(nl1, j + u);
                    float n2 = bcast_f(nl2, j + u);
                    float v = xw[(size_t)s * 64 + lane];
                    acc1 += n1 * v;
                    acc2 += (key & 1) ? n2 * v : 0.0f;
                }
            }
            for (; j < cnt; j++) {
                int key = bcast_i(m, j);
                int s = key >> 1;
                float n1 = bcast_f(nl1, j);
                float n2 = bcast_f(nl2, j);
                float v = xw[(size_t)s * 64 + lane];
                acc1 += n1 * v;
                acc2 += (key & 1) ? n2 * v : 0.0f;
            }
        }
        size_t o = (size_t)n * 64 + lane;
        float v1 = acc1 + self1;
        float v2 = acc2 + self2;
        o1[o] = v1;
        o2[o] = v2;
        sA += (double)v1; qA += (double)v1 * (double)v1;
        sB += (double)v2; qB += (double)v2 * (double)v2;
    }
    __shared__ double l1[4][64], l2[4][64], l3[4][64], l4[4][64];
    l1[w][lane] = sA; l2[w][lane] = qA; l3[w][lane] = sB; l4[w][lane] = qB;
    __syncthreads();
    if (tid < 64) {
        size_t o = (size_t)blockIdx.x * 256;
        part[o + tid]       = l1[0][tid] + l1[1][tid] + l1[2][tid] + l1[3][tid];
        part[o + 64 + tid]  = l2[0][tid] + l2[1][tid] + l2[2][tid] + l2[3][tid];
        part[o + 128 + tid] = l3[0][tid] + l3[1][tid] + l3[2][tid] + l3[3][tid];
        part[o + 192 + tid] = l4[0][tid] + l4[1][tid] + l4[2][tid] + l4[3][tid];
    }
}

// ---------------- bit-domain aggregation (per-node body, r8-verified) ----------------

__device__ inline float bitagg_node(const u64* __restrict__ bits,
                                    const int* __restrict__ em, int shift,
                                    const float* __restrict__ dis,
                                    const float* __restrict__ d2i,
                                    int n, int beg, int end,
                                    int lane, int sh31, bool islo) {
    float disn = dis[n];
    float acc = 0.0f;
    for (int base = beg; base < end; base += 64) {
        int cnt = min(64, end - base);
        unsigned blo = 0, bhi = 0; float nl = 0.0f;
        if (base + lane < end) {
            int m = em[base + lane];
            int s = m >> shift;
            nl = dis[s] * disn;
            u64 b = bits[s];
            blo = (unsigned)b;
            bhi = (unsigned)(b >> 32);
        }
        int j = 0;
        for (; j + 8 <= cnt; j += 8) {
#pragma unroll
            for (int u = 0; u < 8; u++) {
                float nv = bcast_f(nl, j + u);
                unsigned lo = bcast_u(blo, j + u);
                unsigned hi = bcast_u(bhi, j + u);
                unsigned sel = islo ? lo : hi;
                acc += ((sel >> sh31) & 1u) ? nv : 0.0f;
            }
        }
        for (; j < cnt; j++) {
            float nv = bcast_f(nl, j);
            unsigned lo = bcast_u(blo, j);
            unsigned hi = bcast_u(bhi, j);
            unsigned sel = islo ? lo : hi;
            acc += ((sel >> sh31) & 1u) ? nv : 0.0f;
        }
    }
    u64 bn = bits[n];
    unsigned seln = islo ? (unsigned)bn : (unsigned)(bn >> 32);
    acc += ((seln >> sh31) & 1u) ? d2i[n] : 0.0f;
    return acc;
}

// ------ fused: bitagg (into LDS) + dense GEMM + bias + stats ------
// EXACT gemmb_stats_k skeleton (grid NBE, persistent tile-stride loop, register
// stats, stride-17 epilogue); only the sx staging is replaced by in-LDS bitagg.
// A never touches global memory. Bit-identical G and part vs split version.

__global__ __launch_bounds__(256) void fusedL_k(const u64* __restrict__ bits,
                                                const int* __restrict__ em,
                                                int shift,
                                                const float* __restrict__ dis,
                                                const int* __restrict__ rp,
                                                const float* __restrict__ d2i,
                                                const float* __restrict__ W,
                                                const float* __restrict__ bias,
                                                float* __restrict__ G,
                                                double* __restrict__ part,
                                                int pstride, int pbase) {
    __shared__ float smem[4096 + 2112];
    float* sW = smem;
    float* sx = smem + 4096;
    int tid = threadIdx.x, lane = tid & 63, w = tid >> 6;
    const float4* W4 = (const float4*)W;
    float4* sW4 = (float4*)sW;
    for (int i = tid; i < 1024; i += 256) sW4[i] = W4[i];
    int sh31 = lane & 31;
    bool islo = lane < 32;
    int cg = tid & 15, rr = tid >> 4;
    float4 bv = *(const float4*)&bias[cg * 4];
    double s0 = 0, s1 = 0, s2 = 0, s3 = 0, q0 = 0, q1 = 0, q2 = 0, q3 = 0;
    for (int tile = blockIdx.x; tile < NTILE; tile += NBE) {
        __syncthreads();   // prev GEMM done reading sx (and sW staged, 1st iter)
        for (int i = 0; i < 8; i++) {
            int n = tile * 32 + w * 8 + i;
            float acc = bitagg_node(bits, em, shift, dis, d2i, n, rp[n], rp[n + 1],
                                    lane, sh31, islo);
            sx[(w * 8 + i) * 65 + lane] = acc;
        }
        __syncthreads();
        float a0 = bv.x, a1 = bv.y, a2 = bv.z, a3 = bv.w;
        float c0 = bv.x, c1 = bv.y, c2 = bv.z, c3 = bv.w;
#pragma unroll
        for (int k = 0; k < 64; k++) {
            float4 wv = *(const float4*)&sW[k * 64 + cg * 4];
            float xa = sx[rr * 65 + k];
            float xb = sx[(rr + 16) * 65 + k];
            a0 += xa * wv.x; a1 += xa * wv.y; a2 += xa * wv.z; a3 += xa * wv.w;
            c0 += xb * wv.x; c1 += xb * wv.y; c2 += xb * wv.z; c3 += xb * wv.w;
        }
        size_t r0 = (size_t)(tile * 32 + rr) * 64 + cg * 4;
        size_t r1 = (size_t)(tile * 32 + rr + 16) * 64 + cg * 4;
        *(float4*)&G[r0] = make_float4(a0, a1, a2, a3);
        *(float4*)&G[r1] = make_float4(c0, c1, c2, c3);
        s0 += (double)a0; s0 += (double)c0;
        s1 += (double)a1; s1 += (double)c1;
        s2 += (double)a2; s2 += (double)c2;
        s3 += (double)a3; s3 += (double)c3;
        q0 += (double)a0 * (double)a0; q0 += (double)c0 * (double)c0;
        q1 += (double)a1 * (double)a1; q1 += (double)c1 * (double)c1;
        q2 += (double)a2 * (double)a2; q2 += (double)c2 * (double)c2;
        q3 += (double)a3 * (double)a3; q3 += (double)c3 * (double)c3;
    }
    __syncthreads();
    double* sS = (double*)smem;          // 64*17 doubles
    double* sQ = sS + 64 * 17;           // total 17408 B <= 24832 B
    sS[(cg * 4 + 0) * 17 + rr] = s0; sQ[(cg * 4 + 0) * 17 + rr] = q0;
    sS[(cg * 4 + 1) * 17 + rr] = s1; sQ[(cg * 4 + 1) * 17 + rr] = q1;
    sS[(cg * 4 + 2) * 17 + rr] = s2; sQ[(cg * 4 + 2) * 17 + rr] = q2;
    sS[(cg * 4 + 3) * 17 + rr] = s3; sQ[(cg * 4 + 3) * 17 + rr] = q3;
    __syncthreads();
    if (tid < 64) {
        double a = 0.0, b = 0.0;
#pragma unroll
        for (int r = 0; r < 16; r++) { a += sS[tid * 17 + r]; b += sQ[tid * 17 + r]; }
        part[(size_t)blockIdx.x * pstride + pbase + tid] = a;
        part[(size_t)blockIdx.x * pstride + pbase + 64 + tid] = b;
    }
}

// qkv: fused bitagg + three GEMMs, same skeleton (grid NBE, tile-stride loop).
__global__ __launch_bounds__(256) void fused3L_k(const u64* __restrict__ bits,
                                                 const int* __restrict__ em,
                                                 int shift,
                                                 const float* __restrict__ dis,
                                                 const int* __restrict__ rp,
                                                 const float* __restrict__ d2i,
                                                 const float* __restrict__ Wq,
                                                 const float* __restrict__ Wk,
                                                 const float* __restrict__ Wv,
                                                 const float* __restrict__ bq,
                                                 const float* __restrict__ bk,
                                                 const float* __restrict__ bv,
                                                 float* __restrict__ Gq,
                                                 float* __restrict__ Gk,
                                                 float* __restrict__ Gv,
                                                 double* __restrict__ part) {
    __shared__ float smem[3 * 4096 + 2112];   // 57.6 KB
    float* sW = smem;
    float* sx = smem + 3 * 4096;
    int tid = threadIdx.x, lane = tid & 63, w = tid >> 6;
    {
        const float4* A4 = (const float4*)Wq;
        const float4* B4 = (const float4*)Wk;
        const float4* C4 = (const float4*)Wv;
        float4* s4 = (float4*)sW;
        for (int i = tid; i < 1024; i += 256) {
            s4[i] = A4[i];
            s4[1024 + i] = B4[i];
            s4[2048 + i] = C4[i];
        }
    }
    int sh31 = lane & 31;
    bool islo = lane < 32;
    int cg = tid & 15, rr = tid >> 4;
    float4 bvq = *(const float4*)&bq[cg * 4];
    float4 bvk = *(const float4*)&bk[cg * 4];
    float4 bvv = *(const float4*)&bv[cg * 4];
    double sq0 = 0, sq1 = 0, sq2 = 0, sq3 = 0, qq0 = 0, qq1 = 0, qq2 = 0, qq3 = 0;
    double sk0 = 0, sk1 = 0, sk2 = 0, sk3 = 0, qk0 = 0, qk1 = 0, qk2 = 0, qk3 = 0;
    double sv0 = 0, sv1 = 0, sv2 = 0, sv3 = 0, qv0 = 0, qv1 = 0, qv2 = 0, qv3 = 0;
    for (int tile = blockIdx.x; tile < NTILE; tile += NBE) {
        __syncthreads();
        for (int i = 0; i < 8; i++) {
            int n = tile * 32 + w * 8 + i;
            float acc = bitagg_node(bits, em, shift, dis, d2i, n, rp[n], rp[n + 1],
                                    lane, sh31, islo);
            sx[(w * 8 + i) * 65 + lane] = acc;
        }
        __syncthreads();
        float aq0 = bvq.x, aq1 = bvq.y, aq2 = bvq.z, aq3 = bvq.w;
        float cq0 = bvq.x, cq1 = bvq.y, cq2 = bvq.z, cq3 = bvq.w;
        float ak0 = bvk.x, ak1 = bvk.y, ak2 = bvk.z, ak3 = bvk.w;
        float ck0 = bvk.x, ck1 = bvk.y, ck2 = bvk.z, ck3 = bvk.w;
        float av0 = bvv.x, av1 = bvv.y, av2 = bvv.z, av3 = bvv.w;
        float cv0 = bvv.x, cv1 = bvv.y, cv2 = bvv.z, cv3 = bvv.w;
#pragma unroll
        for (int k = 0; k < 64; k++) {
            float4 wq = *(const float4*)&sW[k * 64 + cg * 4];
            float4 wk = *(const float4*)&sW[4096 + k * 64 + cg * 4];
            float4 wv = *(const float4*)&sW[8192 + k * 64 + cg * 4];
            float xa = sx[rr * 65 + k];
            float xb = sx[(rr + 16) * 65 + k];
            aq0 += xa * wq.x; aq1 += xa * wq.y; aq2 += xa * wq.z; aq3 += xa * wq.w;
            cq0 += xb * wq.x; cq1 += xb * wq.y; cq2 += xb * wq.z; cq3 += xb * wq.w;
            ak0 += xa * wk.x; ak1 += xa * wk.y; ak2 += xa * wk.z; ak3 += xa * wk.w;
            ck0 += xb * wk.x; ck1 += xb * wk.y; ck2 += xb * wk.z; ck3 += xb * wk.w;
            av0 += xa * wv.x; av1 += xa * wv.y; av2 += xa * wv.z; av3 += xa * wv.w;
            cv0 += xb * wv.x; cv1 += xb * wv.y; cv2 += xb * wv.z; cv3 += xb * wv.w;
        }
        size_t r0 = (size_t)(tile * 32 + rr) * 64 + cg * 4;
        size_t r1 = (size_t)(tile * 32 + rr + 16) * 64 + cg * 4;
        *(float4*)&Gq[r0] = make_float4(aq0, aq1, aq2, aq3);
        *(float4*)&Gq[r1] = make_float4(cq0, cq1, cq2, cq3);
        *(float4*)&Gk[r0] = make_float4(ak0, ak1, ak2, ak3);
        *(float4*)&Gk[r1] = make_float4(ck0, ck1, ck2, ck3);
        *(float4*)&Gv[r0] = make_float4(av0, av1, av2, av3);
        *(float4*)&Gv[r1] = make_float4(cv0, cv1, cv2, cv3);
        sq0 += (double)aq0; sq0 += (double)cq0;
        sq1 += (double)aq1; sq1 += (double)cq1;
        sq2 += (double)aq2; sq2 += (double)cq2;
        sq3 += (double)aq3; sq3 += (double)cq3;
        qq0 += (double)aq0 * (double)aq0; qq0 += (double)cq0 * (double)cq0;
        qq1 += (double)aq1 * (double)aq1; qq1 += (double)cq1 * (double)cq1;
        qq2 += (double)aq2 * (double)aq2; qq2 += (double)cq2 * (double)cq2;
        qq3 += (double)aq3 * (double)aq3; qq3 += (double)cq3 * (double)cq3;
        sk0 += (double)ak0; sk0 += (double)ck0;
        sk1 += (double)ak1; sk1 += (double)ck1;
        sk2 += (double)ak2; sk2 += (double)ck2;
        sk3 += (double)ak3; sk3 += (double)ck3;
        qk0 += (double)ak0 * (double)ak0; qk0 += (double)ck0 * (double)ck0;
        qk1 += (double)ak1 * (double)ak1; qk1 += (double)ck1 * (double)ck1;
        qk2 += (double)ak2 * (double)ak2; qk2 += (double)ck2 * (double)ck2;
        qk3 += (double)ak3 * (double)ak3; qk3 += (double)ck3 * (double)ck3;
        sv0 += (double)av0; sv0 += (double)cv0;
        sv1 += (double)av1; sv1 += (double)cv1;
        sv2 += (double)av2; sv2 += (double)cv2;
        sv3 += (double)av3; sv3 += (double)cv3;
        qv0 += (double)av0 * (double)av0; qv0 += (double)cv0 * (double)cv0;
        qv1 += (double)av1 * (double)av1; qv1 += (double)cv1 * (double)cv1;
        qv2 += (double)av2 * (double)av2; qv2 += (double)cv2 * (double)cv2;
        qv3 += (double)av3 * (double)av3; qv3 += (double)cv3 * (double)cv3;
    }
    __syncthreads();
    double* sS = (double*)smem;
    double* sQ = sS + 64 * 17;
    // q
    sS[(cg * 4 + 0) * 17 + rr] = sq0; sQ[(cg * 4 + 0) * 17 + rr] = qq0;
    sS[(cg * 4 + 1) * 17 + rr] = sq1; sQ[(cg * 4 + 1) * 17 + rr] = qq1;
    sS[(cg * 4 + 2) * 17 + rr] = sq2; sQ[(cg * 4 + 2) * 17 + rr] = qq2;
    sS[(cg * 4 + 3) * 17 + rr] = sq3; sQ[(cg * 4 + 3) * 17 + rr] = qq3;
    __syncthreads();
    if (tid < 64) {
        double a = 0.0, b = 0.0;
#pragma unroll
        for (int r = 0; r < 16; r++) { a += sS[tid * 17 + r]; b += sQ[tid * 17 + r]; }
        part[(size_t)blockIdx.x * 384 + tid] = a;
        part[(size_t)blockIdx.x * 384 + 64 + tid] = b;
    }
    __syncthreads();
    // k
    sS[(cg * 4 + 0) * 17 + rr] = sk0; sQ[(cg * 4 + 0) * 17 + rr] = qk0;
    sS[(cg * 4 + 1) * 17 + rr] = sk1; sQ[(cg * 4 + 1) * 17 + rr] = qk1;
    sS[(cg * 4 + 2) * 17 + rr] = sk2; sQ[(cg * 4 + 2) * 17 + rr] = qk2;
    sS[(cg * 4 + 3) * 17 + rr] = sk3; sQ[(cg * 4 + 3) * 17 + rr] = qk3;
    __syncthreads();
    if (tid < 64) {
        double a = 0.0, b = 0.0;
#pragma unroll
        for (int r = 0; r < 16; r++) { a += sS[tid * 17 + r]; b += sQ[tid * 17 + r]; }
        part[(size_t)blockIdx.x * 384 + 128 + tid] = a;
        part[(size_t)blockIdx.x * 384 + 192 + tid] = b;
    }
    __syncthreads();
    // v
    sS[(cg * 4 + 0) * 17 + rr] = sv0; sQ[(cg * 4 + 0) * 17 + rr] = qv0;
    sS[(cg * 4 + 1) * 17 + rr] = sv1; sQ[(cg * 4 + 1) * 17 + rr] = qv1;
    sS[(cg * 4 + 2) * 17 + rr] = sv2; sQ[(cg * 4 + 2) * 17 + rr] = qv2;
    sS[(cg * 4 + 3) * 17 + rr] = sv3; sQ[(cg * 4 + 3) * 17 + rr] = qv3;
    __syncthreads();
    if (tid < 64) {
        double a = 0.0, b = 0.0;
#pragma unroll
        for (int r = 0; r < 16; r++) { a += sS[tid * 17 + r]; b += sQ[tid * 17 + r]; }
        part[(size_t)blockIdx.x * 384 + 256 + tid] = a;
        part[(size_t)blockIdx.x * 384 + 320 + tid] = b;
    }
}

// ---------------- deterministic partial reduces ----------------

__global__ __launch_bounds__(256) void bn_red_k(const double* __restrict__ part,
                                                double* __restrict__ st) {
    __shared__ double tr[256];
    int t = threadIdx.x, c = blockIdx.x;
    double s = 0.0;
    for (int b = t; b < NBE; b += 256) s += part[(size_t)b * 128 + c];
    tr[t] = s;
    __syncthreads();
    for (int off = 128; off > 0; off >>= 1) {
        if (t < off) tr[t] += tr[t + off];
        __syncthreads();
    }
    if (t == 0) st[c] = tr[0];
}

__global__ __launch_bounds__(256) void bn_red2_k(const double* __restrict__ part,
                                                 double* __restrict__ sta,
                                                 double* __restrict__ stb) {
    __shared__ double tr[256];
    int t = threadIdx.x, c = blockIdx.x;
    double s = 0.0;
    for (int b = t; b < NBE; b += 256) s += part[(size_t)b * 256 + c];
    tr[t] = s;
    __syncthreads();
    for (int off = 128; off > 0; off >>= 1) {
        if (t < off) tr[t] += tr[t + off];
        __syncthreads();
    }
    if (t == 0) {
        if (c < 128) sta[c] = tr[0];
        else stb[c - 128] = tr[0];
    }
}

__global__ __launch_bounds__(256) void bn_red3_k(const double* __restrict__ part,
                                                 double* __restrict__ sta,
                                                 double* __restrict__ stb,
                                                 double* __restrict__ stc) {
    __shared__ double tr[256];
    int t = threadIdx.x, c = blockIdx.x;
    double s = 0.0;
    for (int b = t; b < NBE; b += 256) s += part[(size_t)b * 384 + c];
    tr[t] = s;
    __syncthreads();
    for (int off = 128; off > 0; off >>= 1) {
        if (t < off) tr[t] += tr[t + off];
        __syncthreads();
    }
    if (t == 0) {
        if (c < 128) sta[c] = tr[0];
        else if (c < 256) stb[c - 128] = tr[0];
        else stc[c - 256] = tr[0];
    }
}

__device__ inline void bn_ss(const double* __restrict__ st, const float* __restrict__ gam,
                             const float* __restrict__ bet, int c,
                             float* __restrict__ ssc, float* __restrict__ ssh) {
    double m = st[c] * (1.0 / NN);
    double v = st[64 + c] * (1.0 / NN) - m * m;
    float scale = (float)((double)gam[c] / sqrt(v + (double)EPSF));
    ssc[c] = scale;
    ssh[c] = bet[c] - (float)m * scale;
}

// ---------------- spike-bit producer kernels ----------------

__global__ __launch_bounds__(256) void lif_spike_k(const float* __restrict__ G,
                                                   const double* __restrict__ st,
                                                   const float* __restrict__ gam,
                                                   const float* __restrict__ bet,
                                                   float* __restrict__ vconv,
                                                   u64* __restrict__ bits) {
    __shared__ float ssc[64], ssh[64];
    int tid = threadIdx.x;
    if (tid < 64) bn_ss(st, gam, bet, tid, ssc, ssh);
    __syncthreads();
    int lane = tid & 63;
    size_t i = (size_t)blockIdx.x * 256 + tid;
    float v = vconv[i] + (G[i] * ssc[lane] + ssh[lane]);
    bool sp = (v - THF >= 0.0f);
    u64 m = __ballot(sp);
    vconv[i] = sp ? 0.0f : v;
    if (lane == 0) bits[i >> 6] = m;
}

__global__ __launch_bounds__(256) void spike_save_k(const float* __restrict__ G,
                                                    const double* __restrict__ st,
                                                    const float* __restrict__ gam,
                                                    const float* __restrict__ bet,
                                                    float* __restrict__ xsave,
                                                    u64* __restrict__ bits) {
    __shared__ float ssc[64], ssh[64];
    int tid = threadIdx.x;
    if (tid < 64) bn_ss(st, gam, bet, tid, ssc, ssh);
    __syncthreads();
    int lane = tid & 63;
    size_t i = (size_t)blockIdx.x * 256 + tid;
    float xv = G[i] * ssc[lane] + ssh[lane];
    xsave[i] = xv;
    u64 m = __ballot(xv - THF >= 0.0f);
    if (lane == 0) bits[i >> 6] = m;
}

__global__ __launch_bounds__(256) void lif_spike_save_k(const float* __restrict__ F,
                                                        const double* __restrict__ st,
                                                        const float* __restrict__ gam,
                                                        const float* __restrict__ bet,
                                                        float* __restrict__ vconv,
                                                        float* __restrict__ xsave,
                                                        u64* __restrict__ bits) {
    __shared__ float ssc[64], ssh[64];
    int tid = threadIdx.x;
    if (tid < 64) bn_ss(st, gam, bet, tid, ssc, ssh);
    __syncthreads();
    int lane = tid & 63;
    size_t i = (size_t)blockIdx.x * 256 + tid;
    float xv = F[i] * ssc[lane] + ssh[lane];
    xsave[i] = xv;
    float v = vconv[i] + xv;
    bool sp = (v - THF >= 0.0f);
    u64 m = __ballot(sp);
    vconv[i] = sp ? 0.0f : v;
    if (lane == 0) bits[i >> 6] = m;
}

__global__ __launch_bounds__(256) void qkv_att_spike_k(const float* __restrict__ Gq,
                                                       const float* __restrict__ Gk,
                                                       const float* __restrict__ Gv,
                                                       const double* __restrict__ st4,
                                                       const double* __restrict__ st5,
                                                       const double* __restrict__ st6,
                                                       const float* __restrict__ gam4,
                                                       const float* __restrict__ bet4,
                                                       const float* __restrict__ gam5,
                                                       const float* __restrict__ bet5,
                                                       const float* __restrict__ gam6,
                                                       const float* __restrict__ bet6,
                                                       u64* __restrict__ bits) {
    __shared__ float sc4[64], sh4[64], sc5[64], sh5[64], sc6[64], sh6[64];
    int tid = threadIdx.x;
    if (tid < 64) {
        bn_ss(st4, gam4, bet4, tid, sc4, sh4);
        bn_ss(st5, gam5, bet5, tid, sc5, sh5);
        bn_ss(st6, gam6, bet6, tid, sc6, sh6);
    }
    __syncthreads();
    int lane = tid & 63;
    size_t i = (size_t)blockIdx.x * 256 + tid;
    bool qb = (Gq[i] * sc4[lane] + sh4[lane] - THF >= 0.0f);
    bool kb = (Gk[i] * sc5[lane] + sh5[lane] - THF >= 0.0f);
    bool vb = (Gv[i] * sc6[lane] + sh6[lane] - THF >= 0.0f);
    int pc = __popcll(__ballot(qb && kb));
    bool qs = ((float)pc * (1.0f / 64.0f) - ATTTH >= 0.0f);
    u64 m = __ballot(vb && qs);
    if (lane == 0) bits[i >> 6] = m;
}

// ---------------- remaining elementwise (with fused stats) ----------------

__global__ __launch_bounds__(256) void bn_add_stats_k(const float* __restrict__ G,
                                                      const double* __restrict__ st,
                                                      const float* __restrict__ gam,
                                                      const float* __restrict__ bet,
                                                      const float* __restrict__ x3,
                                                      float* __restrict__ F,
                                                      double* __restrict__ part) {
    __shared__ float ssc[64], ssh[64];
    int tid = threadIdx.x;
    if (tid < 64) bn_ss(st, gam, bet, tid, ssc, ssh);
    __syncthreads();
    int c = tid & 63;
    double s = 0.0, s2 = 0.0;
    for (size_t i = (size_t)blockIdx.x * 256 + tid; i < NHTOT; i += (size_t)NBE * 256) {
        float f = (G[i] * ssc[c] + ssh[c]) + x3[i];
        F[i] = f;
        s += (double)f;
        s2 += (double)f * (double)f;
    }
    __shared__ double ls[256], lq[256];
    ls[tid] = s; lq[tid] = s2;
    __syncthreads();
    if (tid < 64) {
        double a = ls[tid] + ls[tid + 64] + ls[tid + 128] + ls[tid + 192];
        double b = lq[tid] + lq[tid + 64] + lq[tid + 128] + lq[tid + 192];
        part[(size_t)blockIdx.x * 128 + tid] = a;
        part[(size_t)blockIdx.x * 128 + 64 + tid] = b;
    }
}

__global__ __launch_bounds__(256) void bn_scale_add_stats_k(const float* __restrict__ G,
                                                            const double* __restrict__ st,
                                                            const float* __restrict__ gam,
                                                            const float* __restrict__ bet,
                                                            const float* __restrict__ x4,
                                                            float* __restrict__ tmp2,
                                                            double* __restrict__ part) {
    __shared__ float ssc[64], ssh[64];
    int tid = threadIdx.x;
    if (tid < 64) bn_ss(st, gam, bet, tid, ssc, ssh);
    __syncthreads();
    int c = tid & 63;
    double s = 0.0, s2 = 0.0;
    for (size_t i = (size_t)blockIdx.x * 256 + tid; i < NHTOT; i += (size_t)NBE * 256) {
        float f = x4[i] + 0.125f * (G[i] * ssc[c] + ssh[c]);
        tmp2[i] = f;
        s += (double)f;
        s2 += (double)f * (double)f;
    }
    __shared__ double ls[256], lq[256];
    ls[tid] = s; lq[tid] = s2;
    __syncthreads();
    if (tid < 64) {
        double a = ls[tid] + ls[tid + 64] + ls[tid + 128] + ls[tid + 192];
        double b = lq[tid] + lq[tid + 64] + lq[tid + 128] + lq[tid + 192];
        part[(size_t)blockIdx.x * 128 + tid] = a;
        part[(size_t)blockIdx.x * 128 + 64 + tid] = b;
    }
}

__global__ __launch_bounds__(256) void decode_k(const float* __restrict__ tmp2,
                                                const double* __restrict__ st,
                                                const float* __restrict__ gam,
                                                const float* __restrict__ bet,
                                                const float* __restrict__ wrow,
                                                float* __restrict__ z) {
    __shared__ float ssc[64], ssh[64];
    int tid = threadIdx.x;
    if (tid < 64) bn_ss(st, gam, bet, tid, ssc, ssh);
    __syncthreads();
    int lane = tid & 63;
    int row = blockIdx.x * 4 + (tid >> 6);
    float sv = tmp2[(size_t)row * 64 + lane] * ssc[lane] + ssh[lane];
    float p = sv * wrow[lane];
#pragma unroll
    for (int off = 32; off > 0; off >>= 1) p += __shfl_xor(p, off, 64);
    if (lane == 0) z[row] = p;
}

__global__ void wrow_k(const float* __restrict__ W_lin, float* __restrict__ wrow) {
    int h = threadIdx.x;
    if (h >= 64) return;
    float s = 0.0f;
    for (int j = 0; j < 64; j++) s += W_lin[h * 64 + j];
    wrow[h] = s;
}

// ---------------- host driver ----------------

extern "C" void kernel_launch(void* const* d_in, const int* in_sizes, int n_in,
                              void* d_out, int out_size, void* d_ws, size_t ws_size,
                              hipStream_t stream) {
    const float* x    = (const float*)d_in[0];
    const int* eidx   = (const int*)d_in[1];
    const int* emask  = (const int*)d_in[2];
    const float* Wg   = (const float*)d_in[3];
    const float* bg   = (const float*)d_in[4];
    const float* bng  = (const float*)d_in[5];
    const float* bnb  = (const float*)d_in[6];
    const float* Wlin = (const float*)d_in[7];
    float* zout = (float*)d_out;

    const int* srcp = eidx;
    const int* dstp = eidx + NE;
    const size_t NH = (size_t)NN * HH;

    // ---- workspace layout ----
    float* ws = (float*)d_ws;
    size_t off = 0;
    float* P1 = ws + off; off += NH;
    float* P2 = ws + off; off += NH;
    float* P3 = ws + off; off += NH;
    float* P4 = ws + off; off += NH;
    float* P5 = ws + off; off += NH;
    float* vconv = ws + off; off += NH;
    int* emA = (int*)(ws + off); off += NE;
    int* emB = (int*)(ws + off); off += EM2CAP;
    u64* sbits = (u64*)(ws + off); off += 2 * (size_t)NN;
    double* part = (double*)(ws + off); off += 2 * (size_t)NBE * 384;
    double* stats = (double*)(ws + off); off += 2 * 18 * 128;
    int* rk = (int*)(ws + off); off += NE;
    float* dis1 = ws + off; off += NN;
    float* d21  = ws + off; off += NN;
    float* dis2m = ws + off; off += NN;
    float* d22  = ws + off; off += NN;
    float* wrow = ws + off; off += 64;
    int* rp1 = (int*)(ws + off); off += NN + 2;
    int* rp2 = (int*)(ws + off); off += NN + 2;
    int* cntp = (int*)(ws + off); off += NN;
    int* bsum = (int*)(ws + off); off += 2 * SCAN_B + 4;
    if (off & 1) off++;
    float* P8 = ws + off; off += NH;
    size_t needA2 = off * 4;
    const bool tA2 = (ws_size >= needA2);

    hipMemsetAsync(cntp, 0, NN * sizeof(int), stream);
    hipMemsetAsync(vconv, 0, NH * sizeof(float), stream);

    const int NB_EDGE = NE / 256;
    const int NB_ROW4 = NN / 4;
    const int NB_GEMM = NN / 32;

    wrow_k<<<1, 64, 0, stream>>>(Wlin, wrow);
    hist_k<<<NB_EDGE, 256, 0, stream>>>(dstp, emask, cntp, rk);
    scan1d_k<<<2 * SCAN_B, 256, 0, stream>>>(cntp, rp1, rp2, bsum,
                                             dis1, d21, dis2m, d22);
    scan2d_k<<<1, 512, 0, stream>>>(bsum, rp1, rp2);
    scan3d_k<<<2 * SCAN_B, 256, 0, stream>>>(rp1, rp2, bsum);
    csr_fill_k<<<NB_EDGE, 256, 0, stream>>>(srcp, dstp, emask, rk, rp1, rp2,
                                            emA, emB);
    seg_sort2_k<<<2 * NB_ROW4C, 256, 0, stream>>>(emA, rp1, emB, rp2);

    auto enc = [&](const int* em, int shift, const float* dis, const int* rp,
                   const float* d2i, int bnbase, float* zo, const float* G0pre) {
        auto ST = [&](int bni) { return stats + (bnbase + bni) * 128; };
        auto W = [&](int wi) { return Wg + wi * 4096; };
        auto BI = [&](int wi) { return bg + wi * 64; };
        auto GM = [&](int bi) { return bng + bi * 64; };
        auto BT = [&](int bi) { return bnb + bi * 64; };

        const float* G0 = G0pre;
        if (!G0) {
            gemm_k<<<NB_GEMM, 256, 0, stream>>>(x, W(0), P1);
            gather_stats_k<<<NBE, 256, 0, stream>>>(P1, em, shift, dis, rp, d2i,
                                                    BI(0), P2, part);
            bn_red_k<<<128, 256, 0, stream>>>(part, ST(0));
            G0 = P2;
        }
        // conv_lif (stateful) -> spike bits
        lif_spike_k<<<NB_ROW4, 256, 0, stream>>>(G0, ST(0), GM(0), BT(0), vconv, sbits);
        // layer 1: fused bitagg + GEMM + stats
        fusedL_k<<<NBE, 256, 0, stream>>>(sbits, em, shift, dis, rp, d2i,
                                          W(1), BI(1), P5, part, 128, 0);
        bn_red_k<<<128, 256, 0, stream>>>(part, ST(1));
        // pos branch spike (fresh LIF), keep x2 in P3
        spike_save_k<<<NB_ROW4, 256, 0, stream>>>(P5, ST(1), GM(1), BT(1), P3, sbits);
        // layer 2
        fusedL_k<<<NBE, 256, 0, stream>>>(sbits, em, shift, dis, rp, d2i,
                                          W(2), BI(2), P5, part, 128, 0);
        bn_red_k<<<128, 256, 0, stream>>>(part, ST(2));
        // x4 = BN2(G2) + x2  (F in P4)
        bn_add_stats_k<<<NBE, 256, 0, stream>>>(P5, ST(2), GM(2), BT(2), P3, P4, part);
        bn_red_k<<<128, 256, 0, stream>>>(part, ST(3));
        // x5 = BN3(x4) saved in-place (P4); conv_lif second call -> bits
        lif_spike_save_k<<<NB_ROW4, 256, 0, stream>>>(P4, ST(3), GM(3), BT(3),
                                                      vconv, P4, sbits);
        // q/k/v: ONE fused aggregation + three GEMMs + stats
        fused3L_k<<<NBE, 256, 0, stream>>>(sbits, em, shift, dis, rp, d2i,
                                           W(3), W(4), W(5), BI(3), BI(4), BI(5),
                                           P2, P3, P5, part);
        bn_red3_k<<<384, 256, 0, stream>>>(part, ST(4), ST(5), ST(6));
        qkv_att_spike_k<<<NB_ROW4, 256, 0, stream>>>(P2, P3, P5,
                                                     ST(4), ST(5), ST(6),
                                                     GM(4), BT(4), GM(5), BT(5),
                                                     GM(6), BT(6), sbits);
        // att layer
        fusedL_k<<<NBE, 256, 0, stream>>>(sbits, em, shift, dis, rp, d2i,
                                          W(6), BI(6), P2, part, 128, 0);
        bn_red_k<<<128, 256, 0, stream>>>(part, ST(7));
        bn_scale_add_stats_k<<<NBE, 256, 0, stream>>>(P2, ST(7), GM(7), BT(7),
                                                      P4, P3, part);
        bn_red_k<<<128, 256, 0, stream>>>(part, ST(8));
        decode_k<<<NB_ROW4, 256, 0, stream>>>(P3, ST(8), GM(8), BT(8), wrow, zo);
    };

    if (tA2) {
        // shared L0 traversal: both encs' first (real-valued) aggregation in one pass
        gemm_k<<<NB_GEMM, 256, 0, stream>>>(x, Wg, P1);
        sharedL0_k<<<NBE, 256, 0, stream>>>(P1, emA, rp1, dis1, dis2m, d21, d22,
                                            bg, P2, P8, part);
        bn_red2_k<<<256, 256, 0, stream>>>(part, stats + 0 * 128, stats + 9 * 128);
        enc(emA, 1, dis1, rp1, d21, 0, zout, P2);
        enc(emB, 0, dis2m, rp2, d22, 9, zout + NN, P8);
    } else {
        enc(emA, 1, dis1, rp1, d21, 0, zout, nullptr);
        enc(emB, 0, dis2m, rp2, d22, 9, zout + NN, nullptr);
    }
}

// Round 10
// 1323.429 us; speedup vs baseline: 1.1206x; 1.1206x over previous
//
#include <hip/hip_runtime.h>
#include <math.h>
#include <stdint.h>
#include <limits.h>

#define NN 100000
#define NE 1600000
#define HH 64
#define THF 0.7f
#define ATTTH 0.2f
#define EPSF 1e-5f
#define SCAN_B ((NN + 255) / 256)   // 391
#define EM2CAP 1000000
#define NBE 2048
#define NHTOT ((size_t)NN * 64)
#define NB_ROW4C (NN / 4)
#define NTILE (NN / 32)             // 3125

typedef unsigned long long u64;

// wave-uniform broadcast: v_readlane_b32 (scalar pipe) instead of ds_bpermute.
__device__ inline int bcast_i(int v, int l) {
    return __builtin_amdgcn_readlane(v, l);
}
__device__ inline unsigned bcast_u(unsigned v, int l) {
    return (unsigned)__builtin_amdgcn_readlane((int)v, l);
}
__device__ inline float bcast_f(float v, int l) {
    return __int_as_float(__builtin_amdgcn_readlane(__float_as_int(v), l));
}

// ---------------- setup ----------------

// ONE packed atomic per edge: low16 = all-count, high16 = mask-count.
__global__ void hist_k(const int* __restrict__ dst, const int* __restrict__ mask,
                       int* __restrict__ cntp, int* __restrict__ rk) {
    int e = blockIdx.x * 256 + threadIdx.x;
    if (e >= NE) return;
    int d = dst[e];
    int inc = 1 | ((mask[e] & 1) << 16);
    rk[e] = atomicAdd(&cntp[d], inc);
}

// dual scan over packed counts with fused degree-inverse computation
__global__ void scan1d_k(const int* __restrict__ cntp,
                         int* __restrict__ rp1, int* __restrict__ rp2,
                         int* __restrict__ bsum,
                         float* __restrict__ dis1, float* __restrict__ d21,
                         float* __restrict__ dis2m, float* __restrict__ d22) {
    __shared__ int ls[256];
    int half = (blockIdx.x >= SCAN_B) ? 1 : 0;
    int blk = blockIdx.x - half * SCAN_B;
    int* rp = half ? rp2 : rp1;
    int i = blk * 256 + threadIdx.x;
    int p = (i < NN) ? cntp[i] : 0;
    int v = half ? (p >> 16) : (p & 0xFFFF);
    if (i < NN) {
        float dg = (float)(v + 1);
        float is = 1.0f / sqrtf(dg);
        float iv = 1.0f / dg;
        if (half) { dis2m[i] = is; d22[i] = iv; }
        else      { dis1[i] = is;  d21[i] = iv; }
    }
    ls[threadIdx.x] = v;
    __syncthreads();
    for (int off = 1; off < 256; off <<= 1) {
        int t = (threadIdx.x >= off) ? ls[threadIdx.x - off] : 0;
        __syncthreads();
        ls[threadIdx.x] += t;
        __syncthreads();
    }
    if (i < NN) rp[i] = ls[threadIdx.x] - v;
    if (threadIdx.x == 255) bsum[blockIdx.x] = ls[255];
}

__global__ __launch_bounds__(512) void scan2d_k(int* __restrict__ bsum,
                                                int* __restrict__ rp1,
                                                int* __restrict__ rp2) {
    __shared__ int ls[512];
    int i = threadIdx.x;
    for (int s = 0; s < 2; s++) {
        int v = (i < SCAN_B) ? bsum[s * SCAN_B + i] : 0;
        ls[i] = v;
        __syncthreads();
        for (int off = 1; off < 512; off <<= 1) {
            int t = (i >= off) ? ls[i - off] : 0;
            __syncthreads();
            ls[i] += t;
            __syncthreads();
        }
        if (i < SCAN_B) bsum[s * SCAN_B + i] = ls[i] - v;
        if (i == SCAN_B - 1) { if (s == 0) rp1[NN] = ls[i]; else rp2[NN] = ls[i]; }
        __syncthreads();
    }
}

__global__ void scan3d_k(int* __restrict__ rp1, int* __restrict__ rp2,
                         const int* __restrict__ bsum) {
    int half = (blockIdx.x >= SCAN_B) ? 1 : 0;
    int blk = blockIdx.x - half * SCAN_B;
    int* rp = half ? rp2 : rp1;
    int i = blk * 256 + threadIdx.x;
    if (i < NN) rp[i] += bsum[blockIdx.x];
}

// emA[p] = (src<<1)|mask (all edges); emB[p] = src (masked edges only)
__global__ void csr_fill_k(const int* __restrict__ src, const int* __restrict__ dst,
                           const int* __restrict__ mask, const int* __restrict__ rk,
                           const int* __restrict__ rp1, const int* __restrict__ rp2,
                           int* __restrict__ emA, int* __restrict__ emB) {
    int e = blockIdx.x * 256 + threadIdx.x;
    if (e >= NE) return;
    int s = src[e], d = dst[e];
    int mk = mask[e] & 1;
    int r = rk[e];
    emA[rp1[d] + (r & 0xFFFF)] = (s << 1) | mk;
    if (mk) emB[rp2[d] + (r >> 16)] = s;
}

// sort int segment ascending (keys may duplicate; value IS the key)
__device__ void seg_sort_node(int* __restrict__ em, int beg, int end,
                              int* skey, int lane) {
    int L = end - beg;
    if (L <= 1) return;
    if (L <= 64) {
        int k = (lane < L) ? em[beg + lane] : INT_MAX;
        int rank = 0;
#pragma unroll 8
        for (int r = 0; r < L; r++) {
            int kr = bcast_i(k, r);
            rank += (kr < k || (kr == k && r < lane)) ? 1 : 0;
        }
        if (lane < L) em[beg + rank] = k;
    } else if (L <= 512) {
        for (int i = lane; i < L; i += 64) skey[i] = em[beg + i];
        for (int it = 0; it < L; it++) {
            int par = it & 1;
            for (int p = par + 2 * lane; p + 1 < L; p += 128) {
                int ka = skey[p], kb = skey[p + 1];
                if (kb < ka) { skey[p] = kb; skey[p + 1] = ka; }
            }
        }
        for (int i = lane; i < L; i += 64) em[beg + i] = skey[i];
    }
}

__global__ __launch_bounds__(256) void seg_sort2_k(int* __restrict__ emA,
                                                   const int* __restrict__ rp1,
                                                   int* __restrict__ emB,
                                                   const int* __restrict__ rp2) {
    __shared__ int skey[4][512];
    int tid = threadIdx.x, lane = tid & 63, w = tid >> 6;
    int bid = blockIdx.x;
    if (bid < NB_ROW4C) {
        int n = bid * 4 + w;
        seg_sort_node(emA, rp1[n], rp1[n + 1], skey[w], lane);
    } else {
        int n = (bid - NB_ROW4C) * 4 + w;
        seg_sort_node(emB, rp2[n], rp2[n + 1], skey[w], lane);
    }
}

// ---------------- GEMM (float input, layer 0 only) ----------------

__global__ __launch_bounds__(256) void gemm_k(const float* __restrict__ in,
                                              const float* __restrict__ W,
                                              float* __restrict__ xw) {
    __shared__ float sW[64 * 64];
    __shared__ float sx[32 * 65];
    int tid = threadIdx.x;
    const float4* W4 = (const float4*)W;
    float4* sW4 = (float4*)sW;
    for (int i = tid; i < 1024; i += 256) sW4[i] = W4[i];
    const float* inb = in + (size_t)blockIdx.x * 2048;
    for (int i = tid; i < 2048; i += 256) sx[(i >> 6) * 65 + (i & 63)] = inb[i];
    __syncthreads();
    int cg = tid & 15, rr = tid >> 4;
    float a0 = 0, a1 = 0, a2 = 0, a3 = 0, c0 = 0, c1 = 0, c2 = 0, c3 = 0;
#pragma unroll
    for (int k = 0; k < 64; k++) {
        float4 wv = *(const float4*)&sW[k * 64 + cg * 4];
        float xa = sx[rr * 65 + k];
        float xb = sx[(rr + 16) * 65 + k];
        a0 += xa * wv.x; a1 += xa * wv.y; a2 += xa * wv.z; a3 += xa * wv.w;
        c0 += xb * wv.x; c1 += xb * wv.y; c2 += xb * wv.z; c3 += xb * wv.w;
    }
    size_t r0 = (size_t)(blockIdx.x * 32 + rr) * 64 + cg * 4;
    size_t r1 = (size_t)(blockIdx.x * 32 + rr + 16) * 64 + cg * 4;
    *(float4*)&xw[r0] = make_float4(a0, a1, a2, a3);
    *(float4*)&xw[r1] = make_float4(c0, c1, c2, c3);
}

// ---------------- float gather (fallback L0 only) ----------------

__global__ __launch_bounds__(256) void gather_stats_k(const float* __restrict__ xw,
                                                      const int* __restrict__ em,
                                                      int shift,
                                                      const float* __restrict__ dis,
                                                      const int* __restrict__ rp,
                                                      const float* __restrict__ d2i,
                                                      const float* __restrict__ bias,
                                                      float* __restrict__ out,
                                                      double* __restrict__ part) {
    int tid = threadIdx.x, lane = tid & 63, w = tid >> 6;
    double ps = 0.0, pq = 0.0;
    for (int n = blockIdx.x * 4 + w; n < NN; n += NBE * 4) {
        int beg = rp[n], end = rp[n + 1];
        float disn = dis[n];
        float self = d2i[n] * xw[(size_t)n * 64 + lane] + bias[lane];
        float acc = 0.0f;
        for (int base = beg; base < end; base += 64) {
            int cnt = min(64, end - base);
            int m = 0; float nl = 0.0f;
            if (base + lane < end) {
                m = em[base + lane];
                nl = dis[m >> shift] * disn;
            }
            int j = 0;
            for (; j + 8 <= cnt; j += 8) {
#pragma unroll
                for (int u = 0; u < 8; u++) {
                    int s = bcast_i(m, j + u) >> shift;
                    float nv = bcast_f(nl, j + u);
                    acc += nv * xw[(size_t)s * 64 + lane];
                }
            }
            for (; j < cnt; j++) {
                int s = bcast_i(m, j) >> shift;
                float nv = bcast_f(nl, j);
                acc += nv * xw[(size_t)s * 64 + lane];
            }
        }
        float o = acc + self;
        out[(size_t)n * 64 + lane] = o;
        ps += (double)o;
        pq += (double)o * (double)o;
    }
    __shared__ double ls[4][64], lq[4][64];
    ls[w][lane] = ps; lq[w][lane] = pq;
    __syncthreads();
    if (tid < 64) {
        double a = ls[0][tid] + ls[1][tid] + ls[2][tid] + ls[3][tid];
        double b = lq[0][tid] + lq[1][tid] + lq[2][tid] + lq[3][tid];
        part[(size_t)blockIdx.x * 128 + tid] = a;
        part[(size_t)blockIdx.x * 128 + 64 + tid] = b;
    }
}

// shared L0: one emA traversal -> enc1 + enc2 first aggregation (float rows)
__global__ __launch_bounds__(256) void sharedL0_k(const float* __restrict__ xw,
                                                  const int* __restrict__ em,
                                                  const int* __restrict__ rp,
                                                  const float* __restrict__ dis1,
                                                  const float* __restrict__ dis2m,
                                                  const float* __restrict__ d21,
                                                  const float* __restrict__ d22,
                                                  const float* __restrict__ bias,
                                                  float* __restrict__ o1,
                                                  float* __restrict__ o2,
                                                  double* __restrict__ part) {
    int tid = threadIdx.x, lane = tid & 63, w = tid >> 6;
    double sA = 0.0, qA = 0.0, sB = 0.0, qB = 0.0;
    for (int n = blockIdx.x * 4 + w; n < NN; n += NBE * 4) {
        int beg = rp[n], end = rp[n + 1];
        float disn1 = dis1[n], disn2 = dis2m[n];
        float xv = xw[(size_t)n * 64 + lane];
        float self1 = d21[n] * xv + bias[lane];
        float self2 = d22[n] * xv + bias[lane];
        float acc1 = 0.0f, acc2 = 0.0f;
        for (int base = beg; base < end; base += 64) {
            int cnt = min(64, end - base);
            int m = 0; float nl1 = 0.0f, nl2 = 0.0f;
            if (base + lane < end) {
                m = em[base + lane];
                int s = m >> 1;
                nl1 = dis1[s] * disn1;
                nl2 = dis2m[s] * disn2;
            }
            int j = 0;
            for (; j + 8 <= cnt; j += 8) {
#pragma unroll
                for (int u = 0; u < 8; u++) {
                    int key = bcast_i(m, j + u);
                    int s = key >> 1;
                    float n1 = bcast_f(nl1, j + u);
                    float n2 = bcast_f(nl2, j + u);
                    float v = xw[(size_t)s * 64 + lane];
                    acc1 += n1 * v;
                    acc2 += (key & 1) ? n2 * v : 0.0f;
                }
            }
            for (; j < cnt; j++) {
                int key = bcast_i(m, j);
                int s = key >> 1;
                float n1 = bcast_f(nl1, j);
                float n2 = bcast_f(nl2, j);
                float v = xw[(size_t)s * 64 + lane];
                acc1 += n1 * v;
                acc2 += (key & 1) ? n2 * v : 0.0f;
            }
        }
        size_t o = (size_t)n * 64 + lane;
        float v1 = acc1 + self1;
        float v2 = acc2 + self2;
        o1[o] = v1;
        o2[o] = v2;
        sA += (double)v1; qA += (double)v1 * (double)v1;
        sB += (double)v2; qB += (double)v2 * (double)v2;
    }
    __shared__ double l1[4][64], l2[4][64], l3[4][64], l4[4][64];
    l1[w][lane] = sA; l2[w][lane] = qA; l3[w][lane] = sB; l4[w][lane] = qB;
    __syncthreads();
    if (tid < 64) {
        size_t o = (size_t)blockIdx.x * 256;
        part[o + tid]       = l1[0][tid] + l1[1][tid] + l1[2][tid] + l1[3][tid];
        part[o + 64 + tid]  = l2[0][tid] + l2[1][tid] + l2[2][tid] + l2[3][tid];
        part[o + 128 + tid] = l3[0][tid] + l3[1][tid] + l3[2][tid] + l3[3][tid];
        part[o + 192 + tid] = l4[0][tid] + l4[1][tid] + l4[2][tid] + l4[3][tid];
    }
}

// ---------------- bit-domain aggregation (per-node body, r8-verified) ----------------

__device__ inline float bitagg_node(const u64* __restrict__ bits,
                                    const int* __restrict__ em, int shift,
                                    const float* __restrict__ dis,
                                    const float* __restrict__ d2i,
                                    int n, int beg, int end,
                                    int lane, int sh31, bool islo) {
    float disn = dis[n];
    float acc = 0.0f;
    for (int base = beg; base < end; base += 64) {
        int cnt = min(64, end - base);
        unsigned blo = 0, bhi = 0; float nl = 0.0f;
        if (base + lane < end) {
            int m = em[base + lane];
            int s = m >> shift;
            nl = dis[s] * disn;
            u64 b = bits[s];
            blo = (unsigned)b;
            bhi = (unsigned)(b >> 32);
        }
        int j = 0;
        for (; j + 8 <= cnt; j += 8) {
#pragma unroll
            for (int u = 0; u < 8; u++) {
                float nv = bcast_f(nl, j + u);
                unsigned lo = bcast_u(blo, j + u);
                unsigned hi = bcast_u(bhi, j + u);
                unsigned sel = islo ? lo : hi;
                acc += ((sel >> sh31) & 1u) ? nv : 0.0f;
            }
        }
        for (; j < cnt; j++) {
            float nv = bcast_f(nl, j);
            unsigned lo = bcast_u(blo, j);
            unsigned hi = bcast_u(bhi, j);
            unsigned sel = islo ? lo : hi;
            acc += ((sel >> sh31) & 1u) ? nv : 0.0f;
        }
    }
    u64 bn = bits[n];
    unsigned seln = islo ? (unsigned)bn : (unsigned)(bn >> 32);
    acc += ((seln >> sh31) & 1u) ? d2i[n] : 0.0f;
    return acc;
}

// standalone bit-aggregation (full occupancy; used for qkv triple)
__global__ __launch_bounds__(256) void bitagg_k(const u64* __restrict__ bits,
                                                const int* __restrict__ em,
                                                int shift,
                                                const float* __restrict__ dis,
                                                const int* __restrict__ rp,
                                                const float* __restrict__ d2i,
                                                float* __restrict__ A) {
    int tid = threadIdx.x, lane = tid & 63, w = tid >> 6;
    int sh31 = lane & 31;
    bool islo = lane < 32;
    for (int n = blockIdx.x * 4 + w; n < NN; n += NBE * 4) {
        float acc = bitagg_node(bits, em, shift, dis, d2i, n, rp[n], rp[n + 1],
                                lane, sh31, islo);
        A[(size_t)n * 64 + lane] = acc;
    }
}

// ------ dense [N,64]x[64,64] GEMM + bias + per-column stats (part base/stride) ------
// 24.8 KB LDS -> 6 blocks/CU; stride-17 epilogue (bank-conflict-free).

__global__ __launch_bounds__(256) void gemmb_stats_k(const float* __restrict__ A,
                                                     const float* __restrict__ W,
                                                     const float* __restrict__ bias,
                                                     float* __restrict__ G,
                                                     double* __restrict__ part,
                                                     int pstride, int pbase) {
    __shared__ float smem[4096 + 2112];
    float* sW = smem;
    float* sx = smem + 4096;
    int tid = threadIdx.x;
    const float4* W4 = (const float4*)W;
    float4* sW4 = (float4*)sW;
    for (int i = tid; i < 1024; i += 256) sW4[i] = W4[i];
    int cg = tid & 15, rr = tid >> 4;
    float4 bv = *(const float4*)&bias[cg * 4];
    double s0 = 0, s1 = 0, s2 = 0, s3 = 0, q0 = 0, q1 = 0, q2 = 0, q3 = 0;
    for (int tile = blockIdx.x; tile < NTILE; tile += NBE) {
        const float* Ab = A + (size_t)tile * 2048;
        __syncthreads();
        for (int i = tid; i < 2048; i += 256) sx[(i >> 6) * 65 + (i & 63)] = Ab[i];
        __syncthreads();
        float a0 = bv.x, a1 = bv.y, a2 = bv.z, a3 = bv.w;
        float c0 = bv.x, c1 = bv.y, c2 = bv.z, c3 = bv.w;
#pragma unroll
        for (int k = 0; k < 64; k++) {
            float4 wv = *(const float4*)&sW[k * 64 + cg * 4];
            float xa = sx[rr * 65 + k];
            float xb = sx[(rr + 16) * 65 + k];
            a0 += xa * wv.x; a1 += xa * wv.y; a2 += xa * wv.z; a3 += xa * wv.w;
            c0 += xb * wv.x; c1 += xb * wv.y; c2 += xb * wv.z; c3 += xb * wv.w;
        }
        size_t r0 = (size_t)(tile * 32 + rr) * 64 + cg * 4;
        size_t r1 = (size_t)(tile * 32 + rr + 16) * 64 + cg * 4;
        *(float4*)&G[r0] = make_float4(a0, a1, a2, a3);
        *(float4*)&G[r1] = make_float4(c0, c1, c2, c3);
        s0 += (double)a0; s0 += (double)c0;
        s1 += (double)a1; s1 += (double)c1;
        s2 += (double)a2; s2 += (double)c2;
        s3 += (double)a3; s3 += (double)c3;
        q0 += (double)a0 * (double)a0; q0 += (double)c0 * (double)c0;
        q1 += (double)a1 * (double)a1; q1 += (double)c1 * (double)c1;
        q2 += (double)a2 * (double)a2; q2 += (double)c2 * (double)c2;
        q3 += (double)a3 * (double)a3; q3 += (double)c3 * (double)c3;
    }
    __syncthreads();
    double* sS = (double*)smem;          // 64*17 doubles
    double* sQ = sS + 64 * 17;           // total 17408 B <= 24832 B
    sS[(cg * 4 + 0) * 17 + rr] = s0; sQ[(cg * 4 + 0) * 17 + rr] = q0;
    sS[(cg * 4 + 1) * 17 + rr] = s1; sQ[(cg * 4 + 1) * 17 + rr] = q1;
    sS[(cg * 4 + 2) * 17 + rr] = s2; sQ[(cg * 4 + 2) * 17 + rr] = q2;
    sS[(cg * 4 + 3) * 17 + rr] = s3; sQ[(cg * 4 + 3) * 17 + rr] = q3;
    __syncthreads();
    if (tid < 64) {
        double a = 0.0, b = 0.0;
#pragma unroll
        for (int r = 0; r < 16; r++) { a += sS[tid * 17 + r]; b += sQ[tid * 17 + r]; }
        part[(size_t)blockIdx.x * pstride + pbase + tid] = a;
        part[(size_t)blockIdx.x * pstride + pbase + 64 + tid] = b;
    }
}

// ------ fused: bitagg (into LDS) + dense GEMM + bias + stats (single weight) ------
// 24.8 KB LDS -> 6 blocks/CU. A never touches global memory.

__global__ __launch_bounds__(256) void fusedL_k(const u64* __restrict__ bits,
                                                const int* __restrict__ em,
                                                int shift,
                                                const float* __restrict__ dis,
                                                const int* __restrict__ rp,
                                                const float* __restrict__ d2i,
                                                const float* __restrict__ W,
                                                const float* __restrict__ bias,
                                                float* __restrict__ G,
                                                double* __restrict__ part,
                                                int pstride, int pbase) {
    __shared__ float smem[4096 + 2112];
    float* sW = smem;
    float* sx = smem + 4096;
    int tid = threadIdx.x, lane = tid & 63, w = tid >> 6;
    const float4* W4 = (const float4*)W;
    float4* sW4 = (float4*)sW;
    for (int i = tid; i < 1024; i += 256) sW4[i] = W4[i];
    int sh31 = lane & 31;
    bool islo = lane < 32;
    int cg = tid & 15, rr = tid >> 4;
    float4 bv = *(const float4*)&bias[cg * 4];
    double s0 = 0, s1 = 0, s2 = 0, s3 = 0, q0 = 0, q1 = 0, q2 = 0, q3 = 0;
    for (int tile = blockIdx.x; tile < NTILE; tile += NBE) {
        __syncthreads();   // prev GEMM done reading sx (and sW staged, 1st iter)
        for (int i = 0; i < 8; i++) {
            int n = tile * 32 + w * 8 + i;
            float acc = bitagg_node(bits, em, shift, dis, d2i, n, rp[n], rp[n + 1],
                                    lane, sh31, islo);
            sx[(w * 8 + i) * 65 + lane] = acc;
        }
        __syncthreads();
        float a0 = bv.x, a1 = bv.y, a2 = bv.z, a3 = bv.w;
        float c0 = bv.x, c1 = bv.y, c2 = bv.z, c3 = bv.w;
#pragma unroll
        for (int k = 0; k < 64; k++) {
            float4 wv = *(const float4*)&sW[k * 64 + cg * 4];
            float xa = sx[rr * 65 + k];
            float xb = sx[(rr + 16) * 65 + k];
            a0 += xa * wv.x; a1 += xa * wv.y; a2 += xa * wv.z; a3 += xa * wv.w;
            c0 += xb * wv.x; c1 += xb * wv.y; c2 += xb * wv.z; c3 += xb * wv.w;
        }
        size_t r0 = (size_t)(tile * 32 + rr) * 64 + cg * 4;
        size_t r1 = (size_t)(tile * 32 + rr + 16) * 64 + cg * 4;
        *(float4*)&G[r0] = make_float4(a0, a1, a2, a3);
        *(float4*)&G[r1] = make_float4(c0, c1, c2, c3);
        s0 += (double)a0; s0 += (double)c0;
        s1 += (double)a1; s1 += (double)c1;
        s2 += (double)a2; s2 += (double)c2;
        s3 += (double)a3; s3 += (double)c3;
        q0 += (double)a0 * (double)a0; q0 += (double)c0 * (double)c0;
        q1 += (double)a1 * (double)a1; q1 += (double)c1 * (double)c1;
        q2 += (double)a2 * (double)a2; q2 += (double)c2 * (double)c2;
        q3 += (double)a3 * (double)a3; q3 += (double)c3 * (double)c3;
    }
    __syncthreads();
    double* sS = (double*)smem;          // 64*17 doubles
    double* sQ = sS + 64 * 17;           // total 17408 B <= 24832 B
    sS[(cg * 4 + 0) * 17 + rr] = s0; sQ[(cg * 4 + 0) * 17 + rr] = q0;
    sS[(cg * 4 + 1) * 17 + rr] = s1; sQ[(cg * 4 + 1) * 17 + rr] = q1;
    sS[(cg * 4 + 2) * 17 + rr] = s2; sQ[(cg * 4 + 2) * 17 + rr] = q2;
    sS[(cg * 4 + 3) * 17 + rr] = s3; sQ[(cg * 4 + 3) * 17 + rr] = q3;
    __syncthreads();
    if (tid < 64) {
        double a = 0.0, b = 0.0;
#pragma unroll
        for (int r = 0; r < 16; r++) { a += sS[tid * 17 + r]; b += sQ[tid * 17 + r]; }
        part[(size_t)blockIdx.x * pstride + pbase + tid] = a;
        part[(size_t)blockIdx.x * pstride + pbase + 64 + tid] = b;
    }
}

// ---------------- deterministic partial reduces ----------------

__global__ __launch_bounds__(256) void bn_red_k(const double* __restrict__ part,
                                                double* __restrict__ st) {
    __shared__ double tr[256];
    int t = threadIdx.x, c = blockIdx.x;
    double s = 0.0;
    for (int b = t; b < NBE; b += 256) s += part[(size_t)b * 128 + c];
    tr[t] = s;
    __syncthreads();
    for (int off = 128; off > 0; off >>= 1) {
        if (t < off) tr[t] += tr[t + off];
        __syncthreads();
    }
    if (t == 0) st[c] = tr[0];
}

__global__ __launch_bounds__(256) void bn_red2_k(const double* __restrict__ part,
                                                 double* __restrict__ sta,
                                                 double* __restrict__ stb) {
    __shared__ double tr[256];
    int t = threadIdx.x, c = blockIdx.x;
    double s = 0.0;
    for (int b = t; b < NBE; b += 256) s += part[(size_t)b * 256 + c];
    tr[t] = s;
    __syncthreads();
    for (int off = 128; off > 0; off >>= 1) {
        if (t < off) tr[t] += tr[t + off];
        __syncthreads();
    }
    if (t == 0) {
        if (c < 128) sta[c] = tr[0];
        else stb[c - 128] = tr[0];
    }
}

__global__ __launch_bounds__(256) void bn_red3_k(const double* __restrict__ part,
                                                 double* __restrict__ sta,
                                                 double* __restrict__ stb,
                                                 double* __restrict__ stc) {
    __shared__ double tr[256];
    int t = threadIdx.x, c = blockIdx.x;
    double s = 0.0;
    for (int b = t; b < NBE; b += 256) s += part[(size_t)b * 384 + c];
    tr[t] = s;
    __syncthreads();
    for (int off = 128; off > 0; off >>= 1) {
        if (t < off) tr[t] += tr[t + off];
        __syncthreads();
    }
    if (t == 0) {
        if (c < 128) sta[c] = tr[0];
        else if (c < 256) stb[c - 128] = tr[0];
        else stc[c - 256] = tr[0];
    }
}

__device__ inline void bn_ss(const double* __restrict__ st, const float* __restrict__ gam,
                             const float* __restrict__ bet, int c,
                             float* __restrict__ ssc, float* __restrict__ ssh) {
    double m = st[c] * (1.0 / NN);
    double v = st[64 + c] * (1.0 / NN) - m * m;
    float scale = (float)((double)gam[c] / sqrt(v + (double)EPSF));
    ssc[c] = scale;
    ssh[c] = bet[c] - (float)m * scale;
}

// ---------------- spike-bit producer kernels ----------------

__global__ __launch_bounds__(256) void lif_spike_k(const float* __restrict__ G,
                                                   const double* __restrict__ st,
                                                   const float* __restrict__ gam,
                                                   const float* __restrict__ bet,
                                                   float* __restrict__ vconv,
                                                   u64* __restrict__ bits) {
    __shared__ float ssc[64], ssh[64];
    int tid = threadIdx.x;
    if (tid < 64) bn_ss(st, gam, bet, tid, ssc, ssh);
    __syncthreads();
    int lane = tid & 63;
    size_t i = (size_t)blockIdx.x * 256 + tid;
    float v = vconv[i] + (G[i] * ssc[lane] + ssh[lane]);
    bool sp = (v - THF >= 0.0f);
    u64 m = __ballot(sp);
    vconv[i] = sp ? 0.0f : v;
    if (lane == 0) bits[i >> 6] = m;
}

__global__ __launch_bounds__(256) void spike_save_k(const float* __restrict__ G,
                                                    const double* __restrict__ st,
                                                    const float* __restrict__ gam,
                                                    const float* __restrict__ bet,
                                                    float* __restrict__ xsave,
                                                    u64* __restrict__ bits) {
    __shared__ float ssc[64], ssh[64];
    int tid = threadIdx.x;
    if (tid < 64) bn_ss(st, gam, bet, tid, ssc, ssh);
    __syncthreads();
    int lane = tid & 63;
    size_t i = (size_t)blockIdx.x * 256 + tid;
    float xv = G[i] * ssc[lane] + ssh[lane];
    xsave[i] = xv;
    u64 m = __ballot(xv - THF >= 0.0f);
    if (lane == 0) bits[i >> 6] = m;
}

__global__ __launch_bounds__(256) void lif_spike_save_k(const float* __restrict__ F,
                                                        const double* __restrict__ st,
                                                        const float* __restrict__ gam,
                                                        const float* __restrict__ bet,
                                                        float* __restrict__ vconv,
                                                        float* __restrict__ xsave,
                                                        u64* __restrict__ bits) {
    __shared__ float ssc[64], ssh[64];
    int tid = threadIdx.x;
    if (tid < 64) bn_ss(st, gam, bet, tid, ssc, ssh);
    __syncthreads();
    int lane = tid & 63;
    size_t i = (size_t)blockIdx.x * 256 + tid;
    float xv = F[i] * ssc[lane] + ssh[lane];
    xsave[i] = xv;
    float v = vconv[i] + xv;
    bool sp = (v - THF >= 0.0f);
    u64 m = __ballot(sp);
    vconv[i] = sp ? 0.0f : v;
    if (lane == 0) bits[i >> 6] = m;
}

__global__ __launch_bounds__(256) void qkv_att_spike_k(const float* __restrict__ Gq,
                                                       const float* __restrict__ Gk,
                                                       const float* __restrict__ Gv,
                                                       const double* __restrict__ st4,
                                                       const double* __restrict__ st5,
                                                       const double* __restrict__ st6,
                                                       const float* __restrict__ gam4,
                                                       const float* __restrict__ bet4,
                                                       const float* __restrict__ gam5,
                                                       const float* __restrict__ bet5,
                                                       const float* __restrict__ gam6,
                                                       const float* __restrict__ bet6,
                                                       u64* __restrict__ bits) {
    __shared__ float sc4[64], sh4[64], sc5[64], sh5[64], sc6[64], sh6[64];
    int tid = threadIdx.x;
    if (tid < 64) {
        bn_ss(st4, gam4, bet4, tid, sc4, sh4);
        bn_ss(st5, gam5, bet5, tid, sc5, sh5);
        bn_ss(st6, gam6, bet6, tid, sc6, sh6);
    }
    __syncthreads();
    int lane = tid & 63;
    size_t i = (size_t)blockIdx.x * 256 + tid;
    bool qb = (Gq[i] * sc4[lane] + sh4[lane] - THF >= 0.0f);
    bool kb = (Gk[i] * sc5[lane] + sh5[lane] - THF >= 0.0f);
    bool vb = (Gv[i] * sc6[lane] + sh6[lane] - THF >= 0.0f);
    int pc = __popcll(__ballot(qb && kb));
    bool qs = ((float)pc * (1.0f / 64.0f) - ATTTH >= 0.0f);
    u64 m = __ballot(vb && qs);
    if (lane == 0) bits[i >> 6] = m;
}

// ---------------- remaining elementwise (with fused stats) ----------------

__global__ __launch_bounds__(256) void bn_add_stats_k(const float* __restrict__ G,
                                                      const double* __restrict__ st,
                                                      const float* __restrict__ gam,
                                                      const float* __restrict__ bet,
                                                      const float* __restrict__ x3,
                                                      float* __restrict__ F,
                                                      double* __restrict__ part) {
    __shared__ float ssc[64], ssh[64];
    int tid = threadIdx.x;
    if (tid < 64) bn_ss(st, gam, bet, tid, ssc, ssh);
    __syncthreads();
    int c = tid & 63;
    double s = 0.0, s2 = 0.0;
    for (size_t i = (size_t)blockIdx.x * 256 + tid; i < NHTOT; i += (size_t)NBE * 256) {
        float f = (G[i] * ssc[c] + ssh[c]) + x3[i];
        F[i] = f;
        s += (double)f;
        s2 += (double)f * (double)f;
    }
    __shared__ double ls[256], lq[256];
    ls[tid] = s; lq[tid] = s2;
    __syncthreads();
    if (tid < 64) {
        double a = ls[tid] + ls[tid + 64] + ls[tid + 128] + ls[tid + 192];
        double b = lq[tid] + lq[tid + 64] + lq[tid + 128] + lq[tid + 192];
        part[(size_t)blockIdx.x * 128 + tid] = a;
        part[(size_t)blockIdx.x * 128 + 64 + tid] = b;
    }
}

__global__ __launch_bounds__(256) void bn_scale_add_stats_k(const float* __restrict__ G,
                                                            const double* __restrict__ st,
                                                            const float* __restrict__ gam,
                                                            const float* __restrict__ bet,
                                                            const float* __restrict__ x4,
                                                            float* __restrict__ tmp2,
                                                            double* __restrict__ part) {
    __shared__ float ssc[64], ssh[64];
    int tid = threadIdx.x;
    if (tid < 64) bn_ss(st, gam, bet, tid, ssc, ssh);
    __syncthreads();
    int c = tid & 63;
    double s = 0.0, s2 = 0.0;
    for (size_t i = (size_t)blockIdx.x * 256 + tid; i < NHTOT; i += (size_t)NBE * 256) {
        float f = x4[i] + 0.125f * (G[i] * ssc[c] + ssh[c]);
        tmp2[i] = f;
        s += (double)f;
        s2 += (double)f * (double)f;
    }
    __shared__ double ls[256], lq[256];
    ls[tid] = s; lq[tid] = s2;
    __syncthreads();
    if (tid < 64) {
        double a = ls[tid] + ls[tid + 64] + ls[tid + 128] + ls[tid + 192];
        double b = lq[tid] + lq[tid + 64] + lq[tid + 128] + lq[tid + 192];
        part[(size_t)blockIdx.x * 128 + tid] = a;
        part[(size_t)blockIdx.x * 128 + 64 + tid] = b;
    }
}

__global__ __launch_bounds__(256) void decode_k(const float* __restrict__ tmp2,
                                                const double* __restrict__ st,
                                                const float* __restrict__ gam,
                                                const float* __restrict__ bet,
                                                const float* __restrict__ wrow,
                                                float* __restrict__ z) {
    __shared__ float ssc[64], ssh[64];
    int tid = threadIdx.x;
    if (tid < 64) bn_ss(st, gam, bet, tid, ssc, ssh);
    __syncthreads();
    int lane = tid & 63;
    int row = blockIdx.x * 4 + (tid >> 6);
    float sv = tmp2[(size_t)row * 64 + lane] * ssc[lane] + ssh[lane];
    float p = sv * wrow[lane];
#pragma unroll
    for (int off = 32; off > 0; off >>= 1) p += __shfl_xor(p, off, 64);
    if (lane == 0) z[row] = p;
}

__global__ void wrow_k(const float* __restrict__ W_lin, float* __restrict__ wrow) {
    int h = threadIdx.x;
    if (h >= 64) return;
    float s = 0.0f;
    for (int j = 0; j < 64; j++) s += W_lin[h * 64 + j];
    wrow[h] = s;
}

// ---------------- host driver ----------------

extern "C" void kernel_launch(void* const* d_in, const int* in_sizes, int n_in,
                              void* d_out, int out_size, void* d_ws, size_t ws_size,
                              hipStream_t stream) {
    const float* x    = (const float*)d_in[0];
    const int* eidx   = (const int*)d_in[1];
    const int* emask  = (const int*)d_in[2];
    const float* Wg   = (const float*)d_in[3];
    const float* bg   = (const float*)d_in[4];
    const float* bng  = (const float*)d_in[5];
    const float* bnb  = (const float*)d_in[6];
    const float* Wlin = (const float*)d_in[7];
    float* zout = (float*)d_out;

    const int* srcp = eidx;
    const int* dstp = eidx + NE;
    const size_t NH = (size_t)NN * HH;

    // ---- workspace layout ----
    float* ws = (float*)d_ws;
    size_t off = 0;
    float* P1 = ws + off; off += NH;
    float* P2 = ws + off; off += NH;
    float* P3 = ws + off; off += NH;
    float* P4 = ws + off; off += NH;
    float* P5 = ws + off; off += NH;
    float* vconv = ws + off; off += NH;
    int* emA = (int*)(ws + off); off += NE;
    int* emB = (int*)(ws + off); off += EM2CAP;
    u64* sbits = (u64*)(ws + off); off += 2 * (size_t)NN;
    double* part = (double*)(ws + off); off += 2 * (size_t)NBE * 384;
    double* stats = (double*)(ws + off); off += 2 * 18 * 128;
    int* rk = (int*)(ws + off); off += NE;
    float* dis1 = ws + off; off += NN;
    float* d21  = ws + off; off += NN;
    float* dis2m = ws + off; off += NN;
    float* d22  = ws + off; off += NN;
    float* wrow = ws + off; off += 64;
    int* rp1 = (int*)(ws + off); off += NN + 2;
    int* rp2 = (int*)(ws + off); off += NN + 2;
    int* cntp = (int*)(ws + off); off += NN;
    int* bsum = (int*)(ws + off); off += 2 * SCAN_B + 4;
    if (off & 1) off++;
    float* P8 = ws + off; off += NH;
    size_t needA2 = off * 4;
    const bool tA2 = (ws_size >= needA2);

    hipMemsetAsync(cntp, 0, NN * sizeof(int), stream);
    hipMemsetAsync(vconv, 0, NH * sizeof(float), stream);

    const int NB_EDGE = NE / 256;
    const int NB_ROW4 = NN / 4;
    const int NB_GEMM = NN / 32;

    wrow_k<<<1, 64, 0, stream>>>(Wlin, wrow);
    hist_k<<<NB_EDGE, 256, 0, stream>>>(dstp, emask, cntp, rk);
    scan1d_k<<<2 * SCAN_B, 256, 0, stream>>>(cntp, rp1, rp2, bsum,
                                             dis1, d21, dis2m, d22);
    scan2d_k<<<1, 512, 0, stream>>>(bsum, rp1, rp2);
    scan3d_k<<<2 * SCAN_B, 256, 0, stream>>>(rp1, rp2, bsum);
    csr_fill_k<<<NB_EDGE, 256, 0, stream>>>(srcp, dstp, emask, rk, rp1, rp2,
                                            emA, emB);
    seg_sort2_k<<<2 * NB_ROW4C, 256, 0, stream>>>(emA, rp1, emB, rp2);

    auto enc = [&](const int* em, int shift, const float* dis, const int* rp,
                   const float* d2i, int bnbase, float* zo, const float* G0pre) {
        auto ST = [&](int bni) { return stats + (bnbase + bni) * 128; };
        auto W = [&](int wi) { return Wg + wi * 4096; };
        auto BI = [&](int wi) { return bg + wi * 64; };
        auto GM = [&](int bi) { return bng + bi * 64; };
        auto BT = [&](int bi) { return bnb + bi * 64; };

        const float* G0 = G0pre;
        if (!G0) {
            gemm_k<<<NB_GEMM, 256, 0, stream>>>(x, W(0), P1);
            gather_stats_k<<<NBE, 256, 0, stream>>>(P1, em, shift, dis, rp, d2i,
                                                    BI(0), P2, part);
            bn_red_k<<<128, 256, 0, stream>>>(part, ST(0));
            G0 = P2;
        }
        // conv_lif (stateful) -> spike bits
        lif_spike_k<<<NB_ROW4, 256, 0, stream>>>(G0, ST(0), GM(0), BT(0), vconv, sbits);
        // layer 1: fused bitagg + GEMM + stats
        fusedL_k<<<NBE, 256, 0, stream>>>(sbits, em, shift, dis, rp, d2i,
                                          W(1), BI(1), P5, part, 128, 0);
        bn_red_k<<<128, 256, 0, stream>>>(part, ST(1));
        // pos branch spike (fresh LIF), keep x2 in P3
        spike_save_k<<<NB_ROW4, 256, 0, stream>>>(P5, ST(1), GM(1), BT(1), P3, sbits);
        // layer 2
        fusedL_k<<<NBE, 256, 0, stream>>>(sbits, em, shift, dis, rp, d2i,
                                          W(2), BI(2), P5, part, 128, 0);
        bn_red_k<<<128, 256, 0, stream>>>(part, ST(2));
        // x4 = BN2(G2) + x2  (F in P4)
        bn_add_stats_k<<<NBE, 256, 0, stream>>>(P5, ST(2), GM(2), BT(2), P3, P4, part);
        bn_red_k<<<128, 256, 0, stream>>>(part, ST(3));
        // x5 = BN3(x4) saved in-place (P4); conv_lif second call -> bits
        lif_spike_save_k<<<NB_ROW4, 256, 0, stream>>>(P4, ST(3), GM(3), BT(3),
                                                      vconv, P4, sbits);
        // q/k/v: split path (full-occupancy bitagg + 3 dense GEMMs)
        bitagg_k<<<NBE, 256, 0, stream>>>(sbits, em, shift, dis, rp, d2i, P1);
        gemmb_stats_k<<<NBE, 256, 0, stream>>>(P1, W(3), BI(3), P2, part, 384, 0);
        gemmb_stats_k<<<NBE, 256, 0, stream>>>(P1, W(4), BI(4), P3, part, 384, 128);
        gemmb_stats_k<<<NBE, 256, 0, stream>>>(P1, W(5), BI(5), P5, part, 384, 256);
        bn_red3_k<<<384, 256, 0, stream>>>(part, ST(4), ST(5), ST(6));
        qkv_att_spike_k<<<NB_ROW4, 256, 0, stream>>>(P2, P3, P5,
                                                     ST(4), ST(5), ST(6),
                                                     GM(4), BT(4), GM(5), BT(5),
                                                     GM(6), BT(6), sbits);
        // att layer
        fusedL_k<<<NBE, 256, 0, stream>>>(sbits, em, shift, dis, rp, d2i,
                                          W(6), BI(6), P2, part, 128, 0);
        bn_red_k<<<128, 256, 0, stream>>>(part, ST(7));
        bn_scale_add_stats_k<<<NBE, 256, 0, stream>>>(P2, ST(7), GM(7), BT(7),
                                                      P4, P3, part);
        bn_red_k<<<128, 256, 0, stream>>>(part, ST(8));
        decode_k<<<NB_ROW4, 256, 0, stream>>>(P3, ST(8), GM(8), BT(8), wrow, zo);
    };

    if (tA2) {
        // shared L0 traversal: both encs' first (real-valued) aggregation in one pass
        gemm_k<<<NB_GEMM, 256, 0, stream>>>(x, Wg, P1);
        sharedL0_k<<<NBE, 256, 0, stream>>>(P1, emA, rp1, dis1, dis2m, d21, d22,
                                            bg, P2, P8, part);
        bn_red2_k<<<256, 256, 0, stream>>>(part, stats + 0 * 128, stats + 9 * 128);
        enc(emA, 1, dis1, rp1, d21, 0, zout, P2);
        enc(emB, 0, dis2m, rp2, d22, 9, zout + NN, P8);
    } else {
        enc(emA, 1, dis1, rp1, d21, 0, zout, nullptr);
        enc(emB, 0, dis2m, rp2, d22, 9, zout + NN, nullptr);
    }
}

// Round 11
// 1292.067 us; speedup vs baseline: 1.1478x; 1.0243x over previous
//
#include <hip/hip_runtime.h>
#include <math.h>
#include <stdint.h>
#include <limits.h>

#define NN 100000
#define NE 1600000
#define HH 64
#define THF 0.7f
#define ATTTH 0.2f
#define EPSF 1e-5f
#define SCAN_B ((NN + 255) / 256)   // 391
#define EM2CAP 1000000
#define NBE 2048
#define NHTOT ((size_t)NN * 64)
#define NB_ROW4C (NN / 4)
#define NTILE (NN / 32)             // 3125
#define NT2 ((NTILE + 1) / 2)       // 1563

typedef unsigned long long u64;

// wave-uniform broadcast: v_readlane_b32 (scalar pipe) instead of ds_bpermute.
__device__ inline int bcast_i(int v, int l) {
    return __builtin_amdgcn_readlane(v, l);
}
__device__ inline unsigned bcast_u(unsigned v, int l) {
    return (unsigned)__builtin_amdgcn_readlane((int)v, l);
}
__device__ inline float bcast_f(float v, int l) {
    return __int_as_float(__builtin_amdgcn_readlane(__float_as_int(v), l));
}

// ---------------- setup ----------------

// ONE packed atomic per edge: low16 = all-count, high16 = mask-count.
__global__ void hist_k(const int* __restrict__ dst, const int* __restrict__ mask,
                       int* __restrict__ cntp, int* __restrict__ rk) {
    int e = blockIdx.x * 256 + threadIdx.x;
    if (e >= NE) return;
    int d = dst[e];
    int inc = 1 | ((mask[e] & 1) << 16);
    rk[e] = atomicAdd(&cntp[d], inc);
}

// dual scan over packed counts with fused degree-inverse computation
__global__ void scan1d_k(const int* __restrict__ cntp,
                         int* __restrict__ rp1, int* __restrict__ rp2,
                         int* __restrict__ bsum,
                         float* __restrict__ dis1, float* __restrict__ d21,
                         float* __restrict__ dis2m, float* __restrict__ d22) {
    __shared__ int ls[256];
    int half = (blockIdx.x >= SCAN_B) ? 1 : 0;
    int blk = blockIdx.x - half * SCAN_B;
    int* rp = half ? rp2 : rp1;
    int i = blk * 256 + threadIdx.x;
    int p = (i < NN) ? cntp[i] : 0;
    int v = half ? (p >> 16) : (p & 0xFFFF);
    if (i < NN) {
        float dg = (float)(v + 1);
        float is = 1.0f / sqrtf(dg);
        float iv = 1.0f / dg;
        if (half) { dis2m[i] = is; d22[i] = iv; }
        else      { dis1[i] = is;  d21[i] = iv; }
    }
    ls[threadIdx.x] = v;
    __syncthreads();
    for (int off = 1; off < 256; off <<= 1) {
        int t = (threadIdx.x >= off) ? ls[threadIdx.x - off] : 0;
        __syncthreads();
        ls[threadIdx.x] += t;
        __syncthreads();
    }
    if (i < NN) rp[i] = ls[threadIdx.x] - v;
    if (threadIdx.x == 255) bsum[blockIdx.x] = ls[255];
}

__global__ __launch_bounds__(512) void scan2d_k(int* __restrict__ bsum,
                                                int* __restrict__ rp1,
                                                int* __restrict__ rp2) {
    __shared__ int ls[512];
    int i = threadIdx.x;
    for (int s = 0; s < 2; s++) {
        int v = (i < SCAN_B) ? bsum[s * SCAN_B + i] : 0;
        ls[i] = v;
        __syncthreads();
        for (int off = 1; off < 512; off <<= 1) {
            int t = (i >= off) ? ls[i - off] : 0;
            __syncthreads();
            ls[i] += t;
            __syncthreads();
        }
        if (i < SCAN_B) bsum[s * SCAN_B + i] = ls[i] - v;
        if (i == SCAN_B - 1) { if (s == 0) rp1[NN] = ls[i]; else rp2[NN] = ls[i]; }
        __syncthreads();
    }
}

__global__ void scan3d_k(int* __restrict__ rp1, int* __restrict__ rp2,
                         const int* __restrict__ bsum) {
    int half = (blockIdx.x >= SCAN_B) ? 1 : 0;
    int blk = blockIdx.x - half * SCAN_B;
    int* rp = half ? rp2 : rp1;
    int i = blk * 256 + threadIdx.x;
    if (i < NN) rp[i] += bsum[blockIdx.x];
}

// emA[p] = (src<<1)|mask (all edges); emB[p] = src (masked edges only)
__global__ void csr_fill_k(const int* __restrict__ src, const int* __restrict__ dst,
                           const int* __restrict__ mask, const int* __restrict__ rk,
                           const int* __restrict__ rp1, const int* __restrict__ rp2,
                           int* __restrict__ emA, int* __restrict__ emB) {
    int e = blockIdx.x * 256 + threadIdx.x;
    if (e >= NE) return;
    int s = src[e], d = dst[e];
    int mk = mask[e] & 1;
    int r = rk[e];
    emA[rp1[d] + (r & 0xFFFF)] = (s << 1) | mk;
    if (mk) emB[rp2[d] + (r >> 16)] = s;
}

// sort int segment ascending (keys may duplicate; value IS the key)
__device__ void seg_sort_node(int* __restrict__ em, int beg, int end,
                              int* skey, int lane) {
    int L = end - beg;
    if (L <= 1) return;
    if (L <= 64) {
        int k = (lane < L) ? em[beg + lane] : INT_MAX;
        int rank = 0;
#pragma unroll 8
        for (int r = 0; r < L; r++) {
            int kr = bcast_i(k, r);
            rank += (kr < k || (kr == k && r < lane)) ? 1 : 0;
        }
        if (lane < L) em[beg + rank] = k;
    } else if (L <= 512) {
        for (int i = lane; i < L; i += 64) skey[i] = em[beg + i];
        for (int it = 0; it < L; it++) {
            int par = it & 1;
            for (int p = par + 2 * lane; p + 1 < L; p += 128) {
                int ka = skey[p], kb = skey[p + 1];
                if (kb < ka) { skey[p] = kb; skey[p + 1] = ka; }
            }
        }
        for (int i = lane; i < L; i += 64) em[beg + i] = skey[i];
    }
}

__global__ __launch_bounds__(256) void seg_sort2_k(int* __restrict__ emA,
                                                   const int* __restrict__ rp1,
                                                   int* __restrict__ emB,
                                                   const int* __restrict__ rp2) {
    __shared__ int skey[4][512];
    int tid = threadIdx.x, lane = tid & 63, w = tid >> 6;
    int bid = blockIdx.x;
    if (bid < NB_ROW4C) {
        int n = bid * 4 + w;
        seg_sort_node(emA, rp1[n], rp1[n + 1], skey[w], lane);
    } else {
        int n = (bid - NB_ROW4C) * 4 + w;
        seg_sort_node(emB, rp2[n], rp2[n + 1], skey[w], lane);
    }
}

// ---------------- GEMM (float input, layer 0 only) ----------------

__global__ __launch_bounds__(256) void gemm_k(const float* __restrict__ in,
                                              const float* __restrict__ W,
                                              float* __restrict__ xw) {
    __shared__ float sW[64 * 64];
    __shared__ float sx[32 * 65];
    int tid = threadIdx.x;
    const float4* W4 = (const float4*)W;
    float4* sW4 = (float4*)sW;
    for (int i = tid; i < 1024; i += 256) sW4[i] = W4[i];
    const float* inb = in + (size_t)blockIdx.x * 2048;
    for (int i = tid; i < 2048; i += 256) sx[(i >> 6) * 65 + (i & 63)] = inb[i];
    __syncthreads();
    int cg = tid & 15, rr = tid >> 4;
    float a0 = 0, a1 = 0, a2 = 0, a3 = 0, c0 = 0, c1 = 0, c2 = 0, c3 = 0;
#pragma unroll
    for (int k = 0; k < 64; k++) {
        float4 wv = *(const float4*)&sW[k * 64 + cg * 4];
        float xa = sx[rr * 65 + k];
        float xb = sx[(rr + 16) * 65 + k];
        a0 += xa * wv.x; a1 += xa * wv.y; a2 += xa * wv.z; a3 += xa * wv.w;
        c0 += xb * wv.x; c1 += xb * wv.y; c2 += xb * wv.z; c3 += xb * wv.w;
    }
    size_t r0 = (size_t)(blockIdx.x * 32 + rr) * 64 + cg * 4;
    size_t r1 = (size_t)(blockIdx.x * 32 + rr + 16) * 64 + cg * 4;
    *(float4*)&xw[r0] = make_float4(a0, a1, a2, a3);
    *(float4*)&xw[r1] = make_float4(c0, c1, c2, c3);
}

// ---------------- float gather (fallback L0 only) ----------------

__global__ __launch_bounds__(256) void gather_stats_k(const float* __restrict__ xw,
                                                      const int* __restrict__ em,
                                                      int shift,
                                                      const float* __restrict__ dis,
                                                      const int* __restrict__ rp,
                                                      const float* __restrict__ d2i,
                                                      const float* __restrict__ bias,
                                                      float* __restrict__ out,
                                                      double* __restrict__ part) {
    int tid = threadIdx.x, lane = tid & 63, w = tid >> 6;
    double ps = 0.0, pq = 0.0;
    for (int n = blockIdx.x * 4 + w; n < NN; n += NBE * 4) {
        int beg = rp[n], end = rp[n + 1];
        float disn = dis[n];
        float self = d2i[n] * xw[(size_t)n * 64 + lane] + bias[lane];
        float acc = 0.0f;
        for (int base = beg; base < end; base += 64) {
            int cnt = min(64, end - base);
            int m = 0; float nl = 0.0f;
            if (base + lane < end) {
                m = em[base + lane];
                nl = dis[m >> shift] * disn;
            }
            int j = 0;
            for (; j + 8 <= cnt; j += 8) {
#pragma unroll
                for (int u = 0; u < 8; u++) {
                    int s = bcast_i(m, j + u) >> shift;
                    float nv = bcast_f(nl, j + u);
                    acc += nv * xw[(size_t)s * 64 + lane];
                }
            }
            for (; j < cnt; j++) {
                int s = bcast_i(m, j) >> shift;
                float nv = bcast_f(nl, j);
                acc += nv * xw[(size_t)s * 64 + lane];
            }
        }
        float o = acc + self;
        out[(size_t)n * 64 + lane] = o;
        ps += (double)o;
        pq += (double)o * (double)o;
    }
    __shared__ double ls[4][64], lq[4][64];
    ls[w][lane] = ps; lq[w][lane] = pq;
    __syncthreads();
    if (tid < 64) {
        double a = ls[0][tid] + ls[1][tid] + ls[2][tid] + ls[3][tid];
        double b = lq[0][tid] + lq[1][tid] + lq[2][tid] + lq[3][tid];
        part[(size_t)blockIdx.x * 128 + tid] = a;
        part[(size_t)blockIdx.x * 128 + 64 + tid] = b;
    }
}

// shared L0: one emA traversal -> enc1 + enc2 first aggregation (float rows)
__global__ __launch_bounds__(256) void sharedL0_k(const float* __restrict__ xw,
                                                  const int* __restrict__ em,
                                                  const int* __restrict__ rp,
                                                  const float* __restrict__ dis1,
                                                  const float* __restrict__ dis2m,
                                                  const float* __restrict__ d21,
                                                  const float* __restrict__ d22,
                                                  const float* __restrict__ bias,
                                                  float* __restrict__ o1,
                                                  float* __restrict__ o2,
                                                  double* __restrict__ part) {
    int tid = threadIdx.x, lane = tid & 63, w = tid >> 6;
    double sA = 0.0, qA = 0.0, sB = 0.0, qB = 0.0;
    for (int n = blockIdx.x * 4 + w; n < NN; n += NBE * 4) {
        int beg = rp[n], end = rp[n + 1];
        float disn1 = dis1[n], disn2 = dis2m[n];
        float xv = xw[(size_t)n * 64 + lane];
        float self1 = d21[n] * xv + bias[lane];
        float self2 = d22[n] * xv + bias[lane];
        float acc1 = 0.0f, acc2 = 0.0f;
        for (int base = beg; base < end; base += 64) {
            int cnt = min(64, end - base);
            int m = 0; float nl1 = 0.0f, nl2 = 0.0f;
            if (base + lane < end) {
                m = em[base + lane];
                int s = m >> 1;
                nl1 = dis1[s] * disn1;
                nl2 = dis2m[s] * disn2;
            }
            int j = 0;
            for (; j + 8 <= cnt; j += 8) {
#pragma unroll
                for (int u = 0; u < 8; u++) {
                    int key = bcast_i(m, j + u);
                    int s = key >> 1;
                    float n1 = bcast_f(nl1, j + u);
                    float n2 = bcast_f(nl2, j + u);
                    float v = xw[(size_t)s * 64 + lane];
                    acc1 += n1 * v;
                    acc2 += (key & 1) ? n2 * v : 0.0f;
                }
            }
            for (; j < cnt; j++) {
                int key = bcast_i(m, j);
                int s = key >> 1;
                float n1 = bcast_f(nl1, j);
                float n2 = bcast_f(nl2, j);
                float v = xw[(size_t)s * 64 + lane];
                acc1 += n1 * v;
                acc2 += (key & 1) ? n2 * v : 0.0f;
            }
        }
        size_t o = (size_t)n * 64 + lane;
        float v1 = acc1 + self1;
        float v2 = acc2 + self2;
        o1[o] = v1;
        o2[o] = v2;
        sA += (double)v1; qA += (double)v1 * (double)v1;
        sB += (double)v2; qB += (double)v2 * (double)v2;
    }
    __shared__ double l1[4][64], l2[4][64], l3[4][64], l4[4][64];
    l1[w][lane] = sA; l2[w][lane] = qA; l3[w][lane] = sB; l4[w][lane] = qB;
    __syncthreads();
    if (tid < 64) {
        size_t o = (size_t)blockIdx.x * 256;
        part[o + tid]       = l1[0][tid] + l1[1][tid] + l1[2][tid] + l1[3][tid];
        part[o + 64 + tid]  = l2[0][tid] + l2[1][tid] + l2[2][tid] + l2[3][tid];
        part[o + 128 + tid] = l3[0][tid] + l3[1][tid] + l3[2][tid] + l3[3][tid];
        part[o + 192 + tid] = l4[0][tid] + l4[1][tid] + l4[2][tid] + l4[3][tid];
    }
}

// ---------------- bit-domain aggregation (per-node body, r8-verified) ----------------

__device__ inline float bitagg_node(const u64* __restrict__ bits,
                                    const int* __restrict__ em, int shift,
                                    const float* __restrict__ dis,
                                    const float* __restrict__ d2i,
                                    int n, int beg, int end,
                                    int lane, int sh31, bool islo) {
    float disn = dis[n];
    float acc = 0.0f;
    for (int base = beg; base < end; base += 64) {
        int cnt = min(64, end - base);
        unsigned blo = 0, bhi = 0; float nl = 0.0f;
        if (base + lane < end) {
            int m = em[base + lane];
            int s = m >> shift;
            nl = dis[s] * disn;
            u64 b = bits[s];
            blo = (unsigned)b;
            bhi = (unsigned)(b >> 32);
        }
        int j = 0;
        for (; j + 8 <= cnt; j += 8) {
#pragma unroll
            for (int u = 0; u < 8; u++) {
                float nv = bcast_f(nl, j + u);
                unsigned lo = bcast_u(blo, j + u);
                unsigned hi = bcast_u(bhi, j + u);
                unsigned sel = islo ? lo : hi;
                acc += ((sel >> sh31) & 1u) ? nv : 0.0f;
            }
        }
        for (; j < cnt; j++) {
            float nv = bcast_f(nl, j);
            unsigned lo = bcast_u(blo, j);
            unsigned hi = bcast_u(bhi, j);
            unsigned sel = islo ? lo : hi;
            acc += ((sel >> sh31) & 1u) ? nv : 0.0f;
        }
    }
    u64 bn = bits[n];
    unsigned seln = islo ? (unsigned)bn : (unsigned)(bn >> 32);
    acc += ((seln >> sh31) & 1u) ? d2i[n] : 0.0f;
    return acc;
}

// standalone bit-aggregation (full occupancy; used for qkv triple)
__global__ __launch_bounds__(256) void bitagg_k(const u64* __restrict__ bits,
                                                const int* __restrict__ em,
                                                int shift,
                                                const float* __restrict__ dis,
                                                const int* __restrict__ rp,
                                                const float* __restrict__ d2i,
                                                float* __restrict__ A) {
    int tid = threadIdx.x, lane = tid & 63, w = tid >> 6;
    int sh31 = lane & 31;
    bool islo = lane < 32;
    for (int n = blockIdx.x * 4 + w; n < NN; n += NBE * 4) {
        float acc = bitagg_node(bits, em, shift, dis, d2i, n, rp[n], rp[n + 1],
                                lane, sh31, islo);
        A[(size_t)n * 64 + lane] = acc;
    }
}

// ------ dense [N,64]x[64,64] GEMM + bias + per-column stats (part base/stride) ------
// 24.8 KB LDS -> 6 blocks/CU; stride-17 epilogue (bank-conflict-free).

__global__ __launch_bounds__(256) void gemmb_stats_k(const float* __restrict__ A,
                                                     const float* __restrict__ W,
                                                     const float* __restrict__ bias,
                                                     float* __restrict__ G,
                                                     double* __restrict__ part,
                                                     int pstride, int pbase) {
    __shared__ float smem[4096 + 2112];
    float* sW = smem;
    float* sx = smem + 4096;
    int tid = threadIdx.x;
    const float4* W4 = (const float4*)W;
    float4* sW4 = (float4*)sW;
    for (int i = tid; i < 1024; i += 256) sW4[i] = W4[i];
    int cg = tid & 15, rr = tid >> 4;
    float4 bv = *(const float4*)&bias[cg * 4];
    double s0 = 0, s1 = 0, s2 = 0, s3 = 0, q0 = 0, q1 = 0, q2 = 0, q3 = 0;
    for (int tile = blockIdx.x; tile < NTILE; tile += NBE) {
        const float* Ab = A + (size_t)tile * 2048;
        __syncthreads();
        for (int i = tid; i < 2048; i += 256) sx[(i >> 6) * 65 + (i & 63)] = Ab[i];
        __syncthreads();
        float a0 = bv.x, a1 = bv.y, a2 = bv.z, a3 = bv.w;
        float c0 = bv.x, c1 = bv.y, c2 = bv.z, c3 = bv.w;
#pragma unroll
        for (int k = 0; k < 64; k++) {
            float4 wv = *(const float4*)&sW[k * 64 + cg * 4];
            float xa = sx[rr * 65 + k];
            float xb = sx[(rr + 16) * 65 + k];
            a0 += xa * wv.x; a1 += xa * wv.y; a2 += xa * wv.z; a3 += xa * wv.w;
            c0 += xb * wv.x; c1 += xb * wv.y; c2 += xb * wv.z; c3 += xb * wv.w;
        }
        size_t r0 = (size_t)(tile * 32 + rr) * 64 + cg * 4;
        size_t r1 = (size_t)(tile * 32 + rr + 16) * 64 + cg * 4;
        *(float4*)&G[r0] = make_float4(a0, a1, a2, a3);
        *(float4*)&G[r1] = make_float4(c0, c1, c2, c3);
        s0 += (double)a0; s0 += (double)c0;
        s1 += (double)a1; s1 += (double)c1;
        s2 += (double)a2; s2 += (double)c2;
        s3 += (double)a3; s3 += (double)c3;
        q0 += (double)a0 * (double)a0; q0 += (double)c0 * (double)c0;
        q1 += (double)a1 * (double)a1; q1 += (double)c1 * (double)c1;
        q2 += (double)a2 * (double)a2; q2 += (double)c2 * (double)c2;
        q3 += (double)a3 * (double)a3; q3 += (double)c3 * (double)c3;
    }
    __syncthreads();
    double* sS = (double*)smem;          // 64*17 doubles
    double* sQ = sS + 64 * 17;           // total 17408 B <= 24832 B
    sS[(cg * 4 + 0) * 17 + rr] = s0; sQ[(cg * 4 + 0) * 17 + rr] = q0;
    sS[(cg * 4 + 1) * 17 + rr] = s1; sQ[(cg * 4 + 1) * 17 + rr] = q1;
    sS[(cg * 4 + 2) * 17 + rr] = s2; sQ[(cg * 4 + 2) * 17 + rr] = q2;
    sS[(cg * 4 + 3) * 17 + rr] = s3; sQ[(cg * 4 + 3) * 17 + rr] = q3;
    __syncthreads();
    if (tid < 64) {
        double a = 0.0, b = 0.0;
#pragma unroll
        for (int r = 0; r < 16; r++) { a += sS[tid * 17 + r]; b += sQ[tid * 17 + r]; }
        part[(size_t)blockIdx.x * pstride + pbase + tid] = a;
        part[(size_t)blockIdx.x * pstride + pbase + 64 + tid] = b;
    }
}

// ------ fused: bitagg (into LDS) + dense GEMM + bias + stats, 2 tiles/block ------
// 512 threads = two half-blocks, each one 32-node tile; shared sW (16 KB) +
// 2x sx (8.3 KB) = 32.6 KB -> 4 blocks/CU x 8 waves = 32 waves/CU (cap).
// Per-element math identical to the 256-thread version; stats epilogue
// serializes halves into the shared padded LDS buffer (h0 write, h1 add).

__global__ __launch_bounds__(512, 8) void fusedL_k(const u64* __restrict__ bits,
                                                   const int* __restrict__ em,
                                                   int shift,
                                                   const float* __restrict__ dis,
                                                   const int* __restrict__ rp,
                                                   const float* __restrict__ d2i,
                                                   const float* __restrict__ W,
                                                   const float* __restrict__ bias,
                                                   float* __restrict__ G,
                                                   double* __restrict__ part,
                                                   int pstride, int pbase) {
    __shared__ float smem[4096 + 2 * 2080];   // sW | sx[half0] | sx[half1]
    float* sW = smem;
    int tid = threadIdx.x;
    int h = tid >> 8;             // half 0/1
    int t8 = tid & 255;           // tid within half
    float* sx = smem + 4096 + h * 2080;
    int lane = tid & 63, w8 = t8 >> 6;
    const float4* W4 = (const float4*)W;
    float4* sW4 = (float4*)sW;
    for (int i = tid; i < 1024; i += 512) sW4[i] = W4[i];
    int sh31 = lane & 31;
    bool islo = lane < 32;
    int tile = blockIdx.x * 2 + h;
    bool valid = (tile < NTILE);
    if (valid) {
        for (int i = 0; i < 8; i++) {
            int n = tile * 32 + w8 * 8 + i;
            float acc = bitagg_node(bits, em, shift, dis, d2i, n, rp[n], rp[n + 1],
                                    lane, sh31, islo);
            sx[(w8 * 8 + i) * 65 + lane] = acc;
        }
    }
    __syncthreads();
    int cg = t8 & 15, rr = t8 >> 4;
    double s0 = 0, s1 = 0, s2 = 0, s3 = 0, q0 = 0, q1 = 0, q2 = 0, q3 = 0;
    if (valid) {
        float4 bv = *(const float4*)&bias[cg * 4];
        float a0 = bv.x, a1 = bv.y, a2 = bv.z, a3 = bv.w;
        float c0 = bv.x, c1 = bv.y, c2 = bv.z, c3 = bv.w;
#pragma unroll
        for (int k = 0; k < 64; k++) {
            float4 wv = *(const float4*)&sW[k * 64 + cg * 4];
            float xa = sx[rr * 65 + k];
            float xb = sx[(rr + 16) * 65 + k];
            a0 += xa * wv.x; a1 += xa * wv.y; a2 += xa * wv.z; a3 += xa * wv.w;
            c0 += xb * wv.x; c1 += xb * wv.y; c2 += xb * wv.z; c3 += xb * wv.w;
        }
        size_t r0 = (size_t)(tile * 32 + rr) * 64 + cg * 4;
        size_t r1 = (size_t)(tile * 32 + rr + 16) * 64 + cg * 4;
        *(float4*)&G[r0] = make_float4(a0, a1, a2, a3);
        *(float4*)&G[r1] = make_float4(c0, c1, c2, c3);
        s0 = (double)a0 + (double)c0;
        s1 = (double)a1 + (double)c1;
        s2 = (double)a2 + (double)c2;
        s3 = (double)a3 + (double)c3;
        q0 = (double)a0 * (double)a0 + (double)c0 * (double)c0;
        q1 = (double)a1 * (double)a1 + (double)c1 * (double)c1;
        q2 = (double)a2 * (double)a2 + (double)c2 * (double)c2;
        q3 = (double)a3 * (double)a3 + (double)c3 * (double)c3;
    }
    __syncthreads();
    double* sS = (double*)smem;          // 64*17 doubles (reuses dead sW/sx)
    double* sQ = sS + 64 * 17;
    if (h == 0) {
        sS[(cg * 4 + 0) * 17 + rr] = s0; sQ[(cg * 4 + 0) * 17 + rr] = q0;
        sS[(cg * 4 + 1) * 17 + rr] = s1; sQ[(cg * 4 + 1) * 17 + rr] = q1;
        sS[(cg * 4 + 2) * 17 + rr] = s2; sQ[(cg * 4 + 2) * 17 + rr] = q2;
        sS[(cg * 4 + 3) * 17 + rr] = s3; sQ[(cg * 4 + 3) * 17 + rr] = q3;
    }
    __syncthreads();
    if (h == 1) {
        sS[(cg * 4 + 0) * 17 + rr] += s0; sQ[(cg * 4 + 0) * 17 + rr] += q0;
        sS[(cg * 4 + 1) * 17 + rr] += s1; sQ[(cg * 4 + 1) * 17 + rr] += q1;
        sS[(cg * 4 + 2) * 17 + rr] += s2; sQ[(cg * 4 + 2) * 17 + rr] += q2;
        sS[(cg * 4 + 3) * 17 + rr] += s3; sQ[(cg * 4 + 3) * 17 + rr] += q3;
    }
    __syncthreads();
    if (tid < 64) {
        double a = 0.0, b = 0.0;
#pragma unroll
        for (int r = 0; r < 16; r++) { a += sS[tid * 17 + r]; b += sQ[tid * 17 + r]; }
        part[(size_t)blockIdx.x * pstride + pbase + tid] = a;
        part[(size_t)blockIdx.x * pstride + pbase + 64 + tid] = b;
    }
}

// ---------------- deterministic partial reduces ----------------

__global__ __launch_bounds__(256) void bn_red_k(const double* __restrict__ part,
                                                double* __restrict__ st,
                                                int rows) {
    __shared__ double tr[256];
    int t = threadIdx.x, c = blockIdx.x;
    double s = 0.0;
    for (int b = t; b < rows; b += 256) s += part[(size_t)b * 128 + c];
    tr[t] = s;
    __syncthreads();
    for (int off = 128; off > 0; off >>= 1) {
        if (t < off) tr[t] += tr[t + off];
        __syncthreads();
    }
    if (t == 0) st[c] = tr[0];
}

__global__ __launch_bounds__(256) void bn_red2_k(const double* __restrict__ part,
                                                 double* __restrict__ sta,
                                                 double* __restrict__ stb) {
    __shared__ double tr[256];
    int t = threadIdx.x, c = blockIdx.x;
    double s = 0.0;
    for (int b = t; b < NBE; b += 256) s += part[(size_t)b * 256 + c];
    tr[t] = s;
    __syncthreads();
    for (int off = 128; off > 0; off >>= 1) {
        if (t < off) tr[t] += tr[t + off];
        __syncthreads();
    }
    if (t == 0) {
        if (c < 128) sta[c] = tr[0];
        else stb[c - 128] = tr[0];
    }
}

__global__ __launch_bounds__(256) void bn_red3_k(const double* __restrict__ part,
                                                 double* __restrict__ sta,
                                                 double* __restrict__ stb,
                                                 double* __restrict__ stc) {
    __shared__ double tr[256];
    int t = threadIdx.x, c = blockIdx.x;
    double s = 0.0;
    for (int b = t; b < NBE; b += 256) s += part[(size_t)b * 384 + c];
    tr[t] = s;
    __syncthreads();
    for (int off = 128; off > 0; off >>= 1) {
        if (t < off) tr[t] += tr[t + off];
        __syncthreads();
    }
    if (t == 0) {
        if (c < 128) sta[c] = tr[0];
        else if (c < 256) stb[c - 128] = tr[0];
        else stc[c - 256] = tr[0];
    }
}

__device__ inline void bn_ss(const double* __restrict__ st, const float* __restrict__ gam,
                             const float* __restrict__ bet, int c,
                             float* __restrict__ ssc, float* __restrict__ ssh) {
    double m = st[c] * (1.0 / NN);
    double v = st[64 + c] * (1.0 / NN) - m * m;
    float scale = (float)((double)gam[c] / sqrt(v + (double)EPSF));
    ssc[c] = scale;
    ssh[c] = bet[c] - (float)m * scale;
}

// ---------------- spike-bit producer kernels ----------------

__global__ __launch_bounds__(256) void lif_spike_k(const float* __restrict__ G,
                                                   const double* __restrict__ st,
                                                   const float* __restrict__ gam,
                                                   const float* __restrict__ bet,
                                                   float* __restrict__ vconv,
                                                   u64* __restrict__ bits) {
    __shared__ float ssc[64], ssh[64];
    int tid = threadIdx.x;
    if (tid < 64) bn_ss(st, gam, bet, tid, ssc, ssh);
    __syncthreads();
    int lane = tid & 63;
    size_t i = (size_t)blockIdx.x * 256 + tid;
    float v = vconv[i] + (G[i] * ssc[lane] + ssh[lane]);
    bool sp = (v - THF >= 0.0f);
    u64 m = __ballot(sp);
    vconv[i] = sp ? 0.0f : v;
    if (lane == 0) bits[i >> 6] = m;
}

__global__ __launch_bounds__(256) void spike_save_k(const float* __restrict__ G,
                                                    const double* __restrict__ st,
                                                    const float* __restrict__ gam,
                                                    const float* __restrict__ bet,
                                                    float* __restrict__ xsave,
                                                    u64* __restrict__ bits) {
    __shared__ float ssc[64], ssh[64];
    int tid = threadIdx.x;
    if (tid < 64) bn_ss(st, gam, bet, tid, ssc, ssh);
    __syncthreads();
    int lane = tid & 63;
    size_t i = (size_t)blockIdx.x * 256 + tid;
    float xv = G[i] * ssc[lane] + ssh[lane];
    xsave[i] = xv;
    u64 m = __ballot(xv - THF >= 0.0f);
    if (lane == 0) bits[i >> 6] = m;
}

__global__ __launch_bounds__(256) void lif_spike_save_k(const float* __restrict__ F,
                                                        const double* __restrict__ st,
                                                        const float* __restrict__ gam,
                                                        const float* __restrict__ bet,
                                                        float* __restrict__ vconv,
                                                        float* __restrict__ xsave,
                                                        u64* __restrict__ bits) {
    __shared__ float ssc[64], ssh[64];
    int tid = threadIdx.x;
    if (tid < 64) bn_ss(st, gam, bet, tid, ssc, ssh);
    __syncthreads();
    int lane = tid & 63;
    size_t i = (size_t)blockIdx.x * 256 + tid;
    float xv = F[i] * ssc[lane] + ssh[lane];
    xsave[i] = xv;
    float v = vconv[i] + xv;
    bool sp = (v - THF >= 0.0f);
    u64 m = __ballot(sp);
    vconv[i] = sp ? 0.0f : v;
    if (lane == 0) bits[i >> 6] = m;
}

__global__ __launch_bounds__(256) void qkv_att_spike_k(const float* __restrict__ Gq,
                                                       const float* __restrict__ Gk,
                                                       const float* __restrict__ Gv,
                                                       const double* __restrict__ st4,
                                                       const double* __restrict__ st5,
                                                       const double* __restrict__ st6,
                                                       const float* __restrict__ gam4,
                                                       const float* __restrict__ bet4,
                                                       const float* __restrict__ gam5,
                                                       const float* __restrict__ bet5,
                                                       const float* __restrict__ gam6,
                                                       const float* __restrict__ bet6,
                                                       u64* __restrict__ bits) {
    __shared__ float sc4[64], sh4[64], sc5[64], sh5[64], sc6[64], sh6[64];
    int tid = threadIdx.x;
    if (tid < 64) {
        bn_ss(st4, gam4, bet4, tid, sc4, sh4);
        bn_ss(st5, gam5, bet5, tid, sc5, sh5);
        bn_ss(st6, gam6, bet6, tid, sc6, sh6);
    }
    __syncthreads();
    int lane = tid & 63;
    size_t i = (size_t)blockIdx.x * 256 + tid;
    bool qb = (Gq[i] * sc4[lane] + sh4[lane] - THF >= 0.0f);
    bool kb = (Gk[i] * sc5[lane] + sh5[lane] - THF >= 0.0f);
    bool vb = (Gv[i] * sc6[lane] + sh6[lane] - THF >= 0.0f);
    int pc = __popcll(__ballot(qb && kb));
    bool qs = ((float)pc * (1.0f / 64.0f) - ATTTH >= 0.0f);
    u64 m = __ballot(vb && qs);
    if (lane == 0) bits[i >> 6] = m;
}

// ---------------- remaining elementwise (with fused stats) ----------------

__global__ __launch_bounds__(256) void bn_add_stats_k(const float* __restrict__ G,
                                                      const double* __restrict__ st,
                                                      const float* __restrict__ gam,
                                                      const float* __restrict__ bet,
                                                      const float* __restrict__ x3,
                                                      float* __restrict__ F,
                                                      double* __restrict__ part) {
    __shared__ float ssc[64], ssh[64];
    int tid = threadIdx.x;
    if (tid < 64) bn_ss(st, gam, bet, tid, ssc, ssh);
    __syncthreads();
    int c = tid & 63;
    double s = 0.0, s2 = 0.0;
    for (size_t i = (size_t)blockIdx.x * 256 + tid; i < NHTOT; i += (size_t)NBE * 256) {
        float f = (G[i] * ssc[c] + ssh[c]) + x3[i];
        F[i] = f;
        s += (double)f;
        s2 += (double)f * (double)f;
    }
    __shared__ double ls[256], lq[256];
    ls[tid] = s; lq[tid] = s2;
    __syncthreads();
    if (tid < 64) {
        double a = ls[tid] + ls[tid + 64] + ls[tid + 128] + ls[tid + 192];
        double b = lq[tid] + lq[tid + 64] + lq[tid + 128] + lq[tid + 192];
        part[(size_t)blockIdx.x * 128 + tid] = a;
        part[(size_t)blockIdx.x * 128 + 64 + tid] = b;
    }
}

__global__ __launch_bounds__(256) void bn_scale_add_stats_k(const float* __restrict__ G,
                                                            const double* __restrict__ st,
                                                            const float* __restrict__ gam,
                                                            const float* __restrict__ bet,
                                                            const float* __restrict__ x4,
                                                            float* __restrict__ tmp2,
                                                            double* __restrict__ part) {
    __shared__ float ssc[64], ssh[64];
    int tid = threadIdx.x;
    if (tid < 64) bn_ss(st, gam, bet, tid, ssc, ssh);
    __syncthreads();
    int c = tid & 63;
    double s = 0.0, s2 = 0.0;
    for (size_t i = (size_t)blockIdx.x * 256 + tid; i < NHTOT; i += (size_t)NBE * 256) {
        float f = x4[i] + 0.125f * (G[i] * ssc[c] + ssh[c]);
        tmp2[i] = f;
        s += (double)f;
        s2 += (double)f * (double)f;
    }
    __shared__ double ls[256], lq[256];
    ls[tid] = s; lq[tid] = s2;
    __syncthreads();
    if (tid < 64) {
        double a = ls[tid] + ls[tid + 64] + ls[tid + 128] + ls[tid + 192];
        double b = lq[tid] + lq[tid + 64] + lq[tid + 128] + lq[tid + 192];
        part[(size_t)blockIdx.x * 128 + tid] = a;
        part[(size_t)blockIdx.x * 128 + 64 + tid] = b;
    }
}

__global__ __launch_bounds__(256) void decode_k(const float* __restrict__ tmp2,
                                                const double* __restrict__ st,
                                                const float* __restrict__ gam,
                                                const float* __restrict__ bet,
                                                const float* __restrict__ wrow,
                                                float* __restrict__ z) {
    __shared__ float ssc[64], ssh[64];
    int tid = threadIdx.x;
    if (tid < 64) bn_ss(st, gam, bet, tid, ssc, ssh);
    __syncthreads();
    int lane = tid & 63;
    int row = blockIdx.x * 4 + (tid >> 6);
    float sv = tmp2[(size_t)row * 64 + lane] * ssc[lane] + ssh[lane];
    float p = sv * wrow[lane];
#pragma unroll
    for (int off = 32; off > 0; off >>= 1) p += __shfl_xor(p, off, 64);
    if (lane == 0) z[row] = p;
}

__global__ void wrow_k(const float* __restrict__ W_lin, float* __restrict__ wrow) {
    int h = threadIdx.x;
    if (h >= 64) return;
    float s = 0.0f;
    for (int j = 0; j < 64; j++) s += W_lin[h * 64 + j];
    wrow[h] = s;
}

// ---------------- host driver ----------------

extern "C" void kernel_launch(void* const* d_in, const int* in_sizes, int n_in,
                              void* d_out, int out_size, void* d_ws, size_t ws_size,
                              hipStream_t stream) {
    const float* x    = (const float*)d_in[0];
    const int* eidx   = (const int*)d_in[1];
    const int* emask  = (const int*)d_in[2];
    const float* Wg   = (const float*)d_in[3];
    const float* bg   = (const float*)d_in[4];
    const float* bng  = (const float*)d_in[5];
    const float* bnb  = (const float*)d_in[6];
    const float* Wlin = (const float*)d_in[7];
    float* zout = (float*)d_out;

    const int* srcp = eidx;
    const int* dstp = eidx + NE;
    const size_t NH = (size_t)NN * HH;

    // ---- workspace layout ----
    float* ws = (float*)d_ws;
    size_t off = 0;
    float* P1 = ws + off; off += NH;
    float* P2 = ws + off; off += NH;
    float* P3 = ws + off; off += NH;
    float* P4 = ws + off; off += NH;
    float* P5 = ws + off; off += NH;
    float* vconv = ws + off; off += NH;
    int* emA = (int*)(ws + off); off += NE;
    int* emB = (int*)(ws + off); off += EM2CAP;
    u64* sbits = (u64*)(ws + off); off += 2 * (size_t)NN;
    double* part = (double*)(ws + off); off += 2 * (size_t)NBE * 384;
    double* stats = (double*)(ws + off); off += 2 * 18 * 128;
    int* rk = (int*)(ws + off); off += NE;
    float* dis1 = ws + off; off += NN;
    float* d21  = ws + off; off += NN;
    float* dis2m = ws + off; off += NN;
    float* d22  = ws + off; off += NN;
    float* wrow = ws + off; off += 64;
    int* rp1 = (int*)(ws + off); off += NN + 2;
    int* rp2 = (int*)(ws + off); off += NN + 2;
    int* cntp = (int*)(ws + off); off += NN;
    int* bsum = (int*)(ws + off); off += 2 * SCAN_B + 4;
    if (off & 1) off++;
    float* P8 = ws + off; off += NH;
    size_t needA2 = off * 4;
    const bool tA2 = (ws_size >= needA2);

    hipMemsetAsync(cntp, 0, NN * sizeof(int), stream);
    hipMemsetAsync(vconv, 0, NH * sizeof(float), stream);

    const int NB_EDGE = NE / 256;
    const int NB_ROW4 = NN / 4;
    const int NB_GEMM = NN / 32;

    wrow_k<<<1, 64, 0, stream>>>(Wlin, wrow);
    hist_k<<<NB_EDGE, 256, 0, stream>>>(dstp, emask, cntp, rk);
    scan1d_k<<<2 * SCAN_B, 256, 0, stream>>>(cntp, rp1, rp2, bsum,
                                             dis1, d21, dis2m, d22);
    scan2d_k<<<1, 512, 0, stream>>>(bsum, rp1, rp2);
    scan3d_k<<<2 * SCAN_B, 256, 0, stream>>>(rp1, rp2, bsum);
    csr_fill_k<<<NB_EDGE, 256, 0, stream>>>(srcp, dstp, emask, rk, rp1, rp2,
                                            emA, emB);
    seg_sort2_k<<<2 * NB_ROW4C, 256, 0, stream>>>(emA, rp1, emB, rp2);

    auto enc = [&](const int* em, int shift, const float* dis, const int* rp,
                   const float* d2i, int bnbase, float* zo, const float* G0pre) {
        auto ST = [&](int bni) { return stats + (bnbase + bni) * 128; };
        auto W = [&](int wi) { return Wg + wi * 4096; };
        auto BI = [&](int wi) { return bg + wi * 64; };
        auto GM = [&](int bi) { return bng + bi * 64; };
        auto BT = [&](int bi) { return bnb + bi * 64; };

        const float* G0 = G0pre;
        if (!G0) {
            gemm_k<<<NB_GEMM, 256, 0, stream>>>(x, W(0), P1);
            gather_stats_k<<<NBE, 256, 0, stream>>>(P1, em, shift, dis, rp, d2i,
                                                    BI(0), P2, part);
            bn_red_k<<<128, 256, 0, stream>>>(part, ST(0), NBE);
            G0 = P2;
        }
        // conv_lif (stateful) -> spike bits
        lif_spike_k<<<NB_ROW4, 256, 0, stream>>>(G0, ST(0), GM(0), BT(0), vconv, sbits);
        // layer 1: fused bitagg + GEMM + stats (2 tiles / 512-thread block)
        fusedL_k<<<NT2, 512, 0, stream>>>(sbits, em, shift, dis, rp, d2i,
                                          W(1), BI(1), P5, part, 128, 0);
        bn_red_k<<<128, 256, 0, stream>>>(part, ST(1), NT2);
        // pos branch spike (fresh LIF), keep x2 in P3
        spike_save_k<<<NB_ROW4, 256, 0, stream>>>(P5, ST(1), GM(1), BT(1), P3, sbits);
        // layer 2
        fusedL_k<<<NT2, 512, 0, stream>>>(sbits, em, shift, dis, rp, d2i,
                                          W(2), BI(2), P5, part, 128, 0);
        bn_red_k<<<128, 256, 0, stream>>>(part, ST(2), NT2);
        // x4 = BN2(G2) + x2  (F in P4)
        bn_add_stats_k<<<NBE, 256, 0, stream>>>(P5, ST(2), GM(2), BT(2), P3, P4, part);
        bn_red_k<<<128, 256, 0, stream>>>(part, ST(3), NBE);
        // x5 = BN3(x4) saved in-place (P4); conv_lif second call -> bits
        lif_spike_save_k<<<NB_ROW4, 256, 0, stream>>>(P4, ST(3), GM(3), BT(3),
                                                      vconv, P4, sbits);
        // q/k/v: split path (full-occupancy bitagg + 3 dense GEMMs)
        bitagg_k<<<NBE, 256, 0, stream>>>(sbits, em, shift, dis, rp, d2i, P1);
        gemmb_stats_k<<<NBE, 256, 0, stream>>>(P1, W(3), BI(3), P2, part, 384, 0);
        gemmb_stats_k<<<NBE, 256, 0, stream>>>(P1, W(4), BI(4), P3, part, 384, 128);
        gemmb_stats_k<<<NBE, 256, 0, stream>>>(P1, W(5), BI(5), P5, part, 384, 256);
        bn_red3_k<<<384, 256, 0, stream>>>(part, ST(4), ST(5), ST(6));
        qkv_att_spike_k<<<NB_ROW4, 256, 0, stream>>>(P2, P3, P5,
                                                     ST(4), ST(5), ST(6),
                                                     GM(4), BT(4), GM(5), BT(5),
                                                     GM(6), BT(6), sbits);
        // att layer
        fusedL_k<<<NT2, 512, 0, stream>>>(sbits, em, shift, dis, rp, d2i,
                                          W(6), BI(6), P2, part, 128, 0);
        bn_red_k<<<128, 256, 0, stream>>>(part, ST(7), NT2);
        bn_scale_add_stats_k<<<NBE, 256, 0, stream>>>(P2, ST(7), GM(7), BT(7),
                                                      P4, P3, part);
        bn_red_k<<<128, 256, 0, stream>>>(part, ST(8), NBE);
        decode_k<<<NB_ROW4, 256, 0, stream>>>(P3, ST(8), GM(8), BT(8), wrow, zo);
    };

    if (tA2) {
        // shared L0 traversal: both encs' first (real-valued) aggregation in one pass
        gemm_k<<<NB_GEMM, 256, 0, stream>>>(x, Wg, P1);
        sharedL0_k<<<NBE, 256, 0, stream>>>(P1, emA, rp1, dis1, dis2m, d21, d22,
                                            bg, P2, P8, part);
        bn_red2_k<<<256, 256, 0, stream>>>(part, stats + 0 * 128, stats + 9 * 128);
        enc(emA, 1, dis1, rp1, d21, 0, zout, P2);
        enc(emB, 0, dis2m, rp2, d22, 9, zout + NN, P8);
    } else {
        enc(emA, 1, dis1, rp1, d21, 0, zout, nullptr);
        enc(emB, 0, dis2m, rp2, d22, 9, zout + NN, nullptr);
    }
}

// Round 12
// 1285.152 us; speedup vs baseline: 1.1539x; 1.0054x over previous
//
#include <hip/hip_runtime.h>
#include <math.h>
#include <stdint.h>
#include <limits.h>

#define NN 100000
#define NE 1600000
#define HH 64
#define THF 0.7f
#define ATTTH 0.2f
#define EPSF 1e-5f
#define SCAN_B ((NN + 255) / 256)   // 391
#define EM2CAP 1000000
#define NBE 2048
#define NHTOT ((size_t)NN * 64)
#define NB_ROW4C (NN / 4)
#define NTILE (NN / 32)             // 3125
#define NT2 ((NTILE + 1) / 2)       // 1563

typedef unsigned long long u64;

// wave-uniform broadcast: v_readlane_b32 (scalar pipe) instead of ds_bpermute.
__device__ inline int bcast_i(int v, int l) {
    return __builtin_amdgcn_readlane(v, l);
}
__device__ inline unsigned bcast_u(unsigned v, int l) {
    return (unsigned)__builtin_amdgcn_readlane((int)v, l);
}
__device__ inline float bcast_f(float v, int l) {
    return __int_as_float(__builtin_amdgcn_readlane(__float_as_int(v), l));
}

__device__ inline float lo_f(u64 v) { return __uint_as_float((unsigned)v); }
__device__ inline float hi_f(u64 v) { return __uint_as_float((unsigned)(v >> 32)); }

// ---------------- setup ----------------

// ONE packed atomic per edge: low16 = all-count, high16 = mask-count.
__global__ void hist_k(const int* __restrict__ dst, const int* __restrict__ mask,
                       int* __restrict__ cntp, int* __restrict__ rk) {
    int e = blockIdx.x * 256 + threadIdx.x;
    if (e >= NE) return;
    int d = dst[e];
    int inc = 1 | ((mask[e] & 1) << 16);
    rk[e] = atomicAdd(&cntp[d], inc);
}

// dual scan over packed counts; fused degree-inverse + packed-table init.
// pkA[n] = {bits, dis1, d21}; pkB[n] = {bits, dis2m, d22}; dpk[n] = {dis1, dis2m}.
__global__ void scan1d_k(const int* __restrict__ cntp,
                         int* __restrict__ rp1, int* __restrict__ rp2,
                         int* __restrict__ bsum,
                         float* __restrict__ dis1, float* __restrict__ d21,
                         float* __restrict__ dis2m, float* __restrict__ d22,
                         float* __restrict__ pkAf, float* __restrict__ pkBf,
                         float* __restrict__ dpk) {
    __shared__ int ls[256];
    int half = (blockIdx.x >= SCAN_B) ? 1 : 0;
    int blk = blockIdx.x - half * SCAN_B;
    int* rp = half ? rp2 : rp1;
    int i = blk * 256 + threadIdx.x;
    int p = (i < NN) ? cntp[i] : 0;
    int v = half ? (p >> 16) : (p & 0xFFFF);
    if (i < NN) {
        float dg = (float)(v + 1);
        float is = 1.0f / sqrtf(dg);
        float iv = 1.0f / dg;
        if (half) {
            dis2m[i] = is; d22[i] = iv;
            pkBf[4 * i + 2] = is; pkBf[4 * i + 3] = iv;
            dpk[2 * i + 1] = is;
        } else {
            dis1[i] = is;  d21[i] = iv;
            pkAf[4 * i + 2] = is; pkAf[4 * i + 3] = iv;
            dpk[2 * i + 0] = is;
        }
    }
    ls[threadIdx.x] = v;
    __syncthreads();
    for (int off = 1; off < 256; off <<= 1) {
        int t = (threadIdx.x >= off) ? ls[threadIdx.x - off] : 0;
        __syncthreads();
        ls[threadIdx.x] += t;
        __syncthreads();
    }
    if (i < NN) rp[i] = ls[threadIdx.x] - v;
    if (threadIdx.x == 255) bsum[blockIdx.x] = ls[255];
}

__global__ __launch_bounds__(512) void scan2d_k(int* __restrict__ bsum,
                                                int* __restrict__ rp1,
                                                int* __restrict__ rp2) {
    __shared__ int ls[512];
    int i = threadIdx.x;
    for (int s = 0; s < 2; s++) {
        int v = (i < SCAN_B) ? bsum[s * SCAN_B + i] : 0;
        ls[i] = v;
        __syncthreads();
        for (int off = 1; off < 512; off <<= 1) {
            int t = (i >= off) ? ls[i - off] : 0;
            __syncthreads();
            ls[i] += t;
            __syncthreads();
        }
        if (i < SCAN_B) bsum[s * SCAN_B + i] = ls[i] - v;
        if (i == SCAN_B - 1) { if (s == 0) rp1[NN] = ls[i]; else rp2[NN] = ls[i]; }
        __syncthreads();
    }
}

__global__ void scan3d_k(int* __restrict__ rp1, int* __restrict__ rp2,
                         const int* __restrict__ bsum) {
    int half = (blockIdx.x >= SCAN_B) ? 1 : 0;
    int blk = blockIdx.x - half * SCAN_B;
    int* rp = half ? rp2 : rp1;
    int i = blk * 256 + threadIdx.x;
    if (i < NN) rp[i] += bsum[blockIdx.x];
}

// emA[p] = (src<<1)|mask (all edges); emB[p] = src (masked edges only)
__global__ void csr_fill_k(const int* __restrict__ src, const int* __restrict__ dst,
                           const int* __restrict__ mask, const int* __restrict__ rk,
                           const int* __restrict__ rp1, const int* __restrict__ rp2,
                           int* __restrict__ emA, int* __restrict__ emB) {
    int e = blockIdx.x * 256 + threadIdx.x;
    if (e >= NE) return;
    int s = src[e], d = dst[e];
    int mk = mask[e] & 1;
    int r = rk[e];
    emA[rp1[d] + (r & 0xFFFF)] = (s << 1) | mk;
    if (mk) emB[rp2[d] + (r >> 16)] = s;
}

// sort int segment ascending (keys may duplicate; value IS the key)
__device__ void seg_sort_node(int* __restrict__ em, int beg, int end,
                              int* skey, int lane) {
    int L = end - beg;
    if (L <= 1) return;
    if (L <= 64) {
        int k = (lane < L) ? em[beg + lane] : INT_MAX;
        int rank = 0;
#pragma unroll 8
        for (int r = 0; r < L; r++) {
            int kr = bcast_i(k, r);
            rank += (kr < k || (kr == k && r < lane)) ? 1 : 0;
        }
        if (lane < L) em[beg + rank] = k;
    } else if (L <= 512) {
        for (int i = lane; i < L; i += 64) skey[i] = em[beg + i];
        for (int it = 0; it < L; it++) {
            int par = it & 1;
            for (int p = par + 2 * lane; p + 1 < L; p += 128) {
                int ka = skey[p], kb = skey[p + 1];
                if (kb < ka) { skey[p] = kb; skey[p + 1] = ka; }
            }
        }
        for (int i = lane; i < L; i += 64) em[beg + i] = skey[i];
    }
}

__global__ __launch_bounds__(256) void seg_sort2_k(int* __restrict__ emA,
                                                   const int* __restrict__ rp1,
                                                   int* __restrict__ emB,
                                                   const int* __restrict__ rp2) {
    __shared__ int skey[4][512];
    int tid = threadIdx.x, lane = tid & 63, w = tid >> 6;
    int bid = blockIdx.x;
    if (bid < NB_ROW4C) {
        int n = bid * 4 + w;
        seg_sort_node(emA, rp1[n], rp1[n + 1], skey[w], lane);
    } else {
        int n = (bid - NB_ROW4C) * 4 + w;
        seg_sort_node(emB, rp2[n], rp2[n + 1], skey[w], lane);
    }
}

// ---------------- GEMM (float input, layer 0 only) ----------------

__global__ __launch_bounds__(256) void gemm_k(const float* __restrict__ in,
                                              const float* __restrict__ W,
                                              float* __restrict__ xw) {
    __shared__ float sW[64 * 64];
    __shared__ float sx[32 * 65];
    int tid = threadIdx.x;
    const float4* W4 = (const float4*)W;
    float4* sW4 = (float4*)sW;
    for (int i = tid; i < 1024; i += 256) sW4[i] = W4[i];
    const float* inb = in + (size_t)blockIdx.x * 2048;
    for (int i = tid; i < 2048; i += 256) sx[(i >> 6) * 65 + (i & 63)] = inb[i];
    __syncthreads();
    int cg = tid & 15, rr = tid >> 4;
    float a0 = 0, a1 = 0, a2 = 0, a3 = 0, c0 = 0, c1 = 0, c2 = 0, c3 = 0;
#pragma unroll
    for (int k = 0; k < 64; k++) {
        float4 wv = *(const float4*)&sW[k * 64 + cg * 4];
        float xa = sx[rr * 65 + k];
        float xb = sx[(rr + 16) * 65 + k];
        a0 += xa * wv.x; a1 += xa * wv.y; a2 += xa * wv.z; a3 += xa * wv.w;
        c0 += xb * wv.x; c1 += xb * wv.y; c2 += xb * wv.z; c3 += xb * wv.w;
    }
    size_t r0 = (size_t)(blockIdx.x * 32 + rr) * 64 + cg * 4;
    size_t r1 = (size_t)(blockIdx.x * 32 + rr + 16) * 64 + cg * 4;
    *(float4*)&xw[r0] = make_float4(a0, a1, a2, a3);
    *(float4*)&xw[r1] = make_float4(c0, c1, c2, c3);
}

// ---------------- float gather (fallback L0 only) ----------------

__global__ __launch_bounds__(256) void gather_stats_k(const float* __restrict__ xw,
                                                      const int* __restrict__ em,
                                                      int shift,
                                                      const float* __restrict__ dis,
                                                      const int* __restrict__ rp,
                                                      const float* __restrict__ d2i,
                                                      const float* __restrict__ bias,
                                                      float* __restrict__ out,
                                                      double* __restrict__ part) {
    int tid = threadIdx.x, lane = tid & 63, w = tid >> 6;
    double ps = 0.0, pq = 0.0;
    for (int n = blockIdx.x * 4 + w; n < NN; n += NBE * 4) {
        int beg = rp[n], end = rp[n + 1];
        float disn = dis[n];
        float self = d2i[n] * xw[(size_t)n * 64 + lane] + bias[lane];
        float acc = 0.0f;
        for (int base = beg; base < end; base += 64) {
            int cnt = min(64, end - base);
            int m = 0; float nl = 0.0f;
            if (base + lane < end) {
                m = em[base + lane];
                nl = dis[m >> shift] * disn;
            }
            int j = 0;
            for (; j + 8 <= cnt; j += 8) {
#pragma unroll
                for (int u = 0; u < 8; u++) {
                    int s = bcast_i(m, j + u) >> shift;
                    float nv = bcast_f(nl, j + u);
                    acc += nv * xw[(size_t)s * 64 + lane];
                }
            }
            for (; j < cnt; j++) {
                int s = bcast_i(m, j) >> shift;
                float nv = bcast_f(nl, j);
                acc += nv * xw[(size_t)s * 64 + lane];
            }
        }
        float o = acc + self;
        out[(size_t)n * 64 + lane] = o;
        ps += (double)o;
        pq += (double)o * (double)o;
    }
    __shared__ double ls[4][64], lq[4][64];
    ls[w][lane] = ps; lq[w][lane] = pq;
    __syncthreads();
    if (tid < 64) {
        double a = ls[0][tid] + ls[1][tid] + ls[2][tid] + ls[3][tid];
        double b = lq[0][tid] + lq[1][tid] + lq[2][tid] + lq[3][tid];
        part[(size_t)blockIdx.x * 128 + tid] = a;
        part[(size_t)blockIdx.x * 128 + 64 + tid] = b;
    }
}

// shared L0: one emA traversal -> enc1 + enc2 first aggregation (float rows).
// Per-edge norms come from the packed float2 table (one 8B random load).
__global__ __launch_bounds__(256) void sharedL0_k(const float* __restrict__ xw,
                                                  const int* __restrict__ em,
                                                  const int* __restrict__ rp,
                                                  const float2* __restrict__ dpk,
                                                  const float* __restrict__ dis1,
                                                  const float* __restrict__ dis2m,
                                                  const float* __restrict__ d21,
                                                  const float* __restrict__ d22,
                                                  const float* __restrict__ bias,
                                                  float* __restrict__ o1,
                                                  float* __restrict__ o2,
                                                  double* __restrict__ part) {
    int tid = threadIdx.x, lane = tid & 63, w = tid >> 6;
    double sA = 0.0, qA = 0.0, sB = 0.0, qB = 0.0;
    for (int n = blockIdx.x * 4 + w; n < NN; n += NBE * 4) {
        int beg = rp[n], end = rp[n + 1];
        float disn1 = dis1[n], disn2 = dis2m[n];
        float xv = xw[(size_t)n * 64 + lane];
        float self1 = d21[n] * xv + bias[lane];
        float self2 = d22[n] * xv + bias[lane];
        float acc1 = 0.0f, acc2 = 0.0f;
        for (int base = beg; base < end; base += 64) {
            int cnt = min(64, end - base);
            int m = 0; float nl1 = 0.0f, nl2 = 0.0f;
            if (base + lane < end) {
                m = em[base + lane];
                int s = m >> 1;
                float2 dd = dpk[s];
                nl1 = dd.x * disn1;
                nl2 = dd.y * disn2;
            }
            int j = 0;
            for (; j + 8 <= cnt; j += 8) {
#pragma unroll
                for (int u = 0; u < 8; u++) {
                    int key = bcast_i(m, j + u);
                    int s = key >> 1;
                    float n1 = bcast_f(nl1, j + u);
                    float n2 = bcast_f(nl2, j + u);
                    float v = xw[(size_t)s * 64 + lane];
                    acc1 += n1 * v;
                    acc2 += (key & 1) ? n2 * v : 0.0f;
                }
            }
            for (; j < cnt; j++) {
                int key = bcast_i(m, j);
                int s = key >> 1;
                float n1 = bcast_f(nl1, j);
                float n2 = bcast_f(nl2, j);
                float v = xw[(size_t)s * 64 + lane];
                acc1 += n1 * v;
                acc2 += (key & 1) ? n2 * v : 0.0f;
            }
        }
        size_t o = (size_t)n * 64 + lane;
        float v1 = acc1 + self1;
        float v2 = acc2 + self2;
        o1[o] = v1;
        o2[o] = v2;
        sA += (double)v1; qA += (double)v1 * (double)v1;
        sB += (double)v2; qB += (double)v2 * (double)v2;
    }
    __shared__ double l1[4][64], l2[4][64], l3[4][64], l4[4][64];
    l1[w][lane] = sA; l2[w][lane] = qA; l3[w][lane] = sB; l4[w][lane] = qB;
    __syncthreads();
    if (tid < 64) {
        size_t o = (size_t)blockIdx.x * 256;
        part[o + tid]       = l1[0][tid] + l1[1][tid] + l1[2][tid] + l1[3][tid];
        part[o + 64 + tid]  = l2[0][tid] + l2[1][tid] + l2[2][tid] + l2[3][tid];
        part[o + 128 + tid] = l3[0][tid] + l3[1][tid] + l3[2][tid] + l3[3][tid];
        part[o + 192 + tid] = l4[0][tid] + l4[1][tid] + l4[2][tid] + l4[3][tid];
    }
}

// -------- bit-domain aggregation over packed node records --------
// pk[n] = {bits(u64), dis(f32), d2i(f32)}: ONE 16B random load per edge
// (replaces bits[s] + dis[s]); one per node for the prologue/self-term.

__device__ inline float bitagg_nodeP(const ulonglong2* __restrict__ pk,
                                     const int* __restrict__ em, int shift,
                                     int n, int beg, int end,
                                     int lane, int sh31, bool islo) {
    ulonglong2 pn = pk[n];
    float disn = lo_f(pn.y);
    float acc = 0.0f;
    for (int base = beg; base < end; base += 64) {
        int cnt = min(64, end - base);
        unsigned blo = 0, bhi = 0; float nl = 0.0f;
        if (base + lane < end) {
            int m = em[base + lane];
            int s = m >> shift;
            ulonglong2 ps = pk[s];
            nl = lo_f(ps.y) * disn;
            blo = (unsigned)ps.x;
            bhi = (unsigned)(ps.x >> 32);
        }
        int j = 0;
        for (; j + 8 <= cnt; j += 8) {
#pragma unroll
            for (int u = 0; u < 8; u++) {
                float nv = bcast_f(nl, j + u);
                unsigned lo = bcast_u(blo, j + u);
                unsigned hi = bcast_u(bhi, j + u);
                unsigned sel = islo ? lo : hi;
                acc += ((sel >> sh31) & 1u) ? nv : 0.0f;
            }
        }
        for (; j < cnt; j++) {
            float nv = bcast_f(nl, j);
            unsigned lo = bcast_u(blo, j);
            unsigned hi = bcast_u(bhi, j);
            unsigned sel = islo ? lo : hi;
            acc += ((sel >> sh31) & 1u) ? nv : 0.0f;
        }
    }
    unsigned seln = islo ? (unsigned)pn.x : (unsigned)(pn.x >> 32);
    acc += ((seln >> sh31) & 1u) ? hi_f(pn.y) : 0.0f;
    return acc;
}

// standalone bit-aggregation (full occupancy; used for qkv triple)
__global__ __launch_bounds__(256) void bitagg_k(const ulonglong2* __restrict__ pk,
                                                const int* __restrict__ em,
                                                int shift,
                                                const int* __restrict__ rp,
                                                float* __restrict__ A) {
    int tid = threadIdx.x, lane = tid & 63, w = tid >> 6;
    int sh31 = lane & 31;
    bool islo = lane < 32;
    for (int n = blockIdx.x * 4 + w; n < NN; n += NBE * 4) {
        float acc = bitagg_nodeP(pk, em, shift, n, rp[n], rp[n + 1],
                                 lane, sh31, islo);
        A[(size_t)n * 64 + lane] = acc;
    }
}

// ------ dense [N,64]x[64,64] GEMM + bias + per-column stats (part base/stride) ------
// 24.8 KB LDS -> 6 blocks/CU; stride-17 epilogue (bank-conflict-free).

__global__ __launch_bounds__(256) void gemmb_stats_k(const float* __restrict__ A,
                                                     const float* __restrict__ W,
                                                     const float* __restrict__ bias,
                                                     float* __restrict__ G,
                                                     double* __restrict__ part,
                                                     int pstride, int pbase) {
    __shared__ float smem[4096 + 2112];
    float* sW = smem;
    float* sx = smem + 4096;
    int tid = threadIdx.x;
    const float4* W4 = (const float4*)W;
    float4* sW4 = (float4*)sW;
    for (int i = tid; i < 1024; i += 256) sW4[i] = W4[i];
    int cg = tid & 15, rr = tid >> 4;
    float4 bv = *(const float4*)&bias[cg * 4];
    double s0 = 0, s1 = 0, s2 = 0, s3 = 0, q0 = 0, q1 = 0, q2 = 0, q3 = 0;
    for (int tile = blockIdx.x; tile < NTILE; tile += NBE) {
        const float* Ab = A + (size_t)tile * 2048;
        __syncthreads();
        for (int i = tid; i < 2048; i += 256) sx[(i >> 6) * 65 + (i & 63)] = Ab[i];
        __syncthreads();
        float a0 = bv.x, a1 = bv.y, a2 = bv.z, a3 = bv.w;
        float c0 = bv.x, c1 = bv.y, c2 = bv.z, c3 = bv.w;
#pragma unroll
        for (int k = 0; k < 64; k++) {
            float4 wv = *(const float4*)&sW[k * 64 + cg * 4];
            float xa = sx[rr * 65 + k];
            float xb = sx[(rr + 16) * 65 + k];
            a0 += xa * wv.x; a1 += xa * wv.y; a2 += xa * wv.z; a3 += xa * wv.w;
            c0 += xb * wv.x; c1 += xb * wv.y; c2 += xb * wv.z; c3 += xb * wv.w;
        }
        size_t r0 = (size_t)(tile * 32 + rr) * 64 + cg * 4;
        size_t r1 = (size_t)(tile * 32 + rr + 16) * 64 + cg * 4;
        *(float4*)&G[r0] = make_float4(a0, a1, a2, a3);
        *(float4*)&G[r1] = make_float4(c0, c1, c2, c3);
        s0 += (double)a0; s0 += (double)c0;
        s1 += (double)a1; s1 += (double)c1;
        s2 += (double)a2; s2 += (double)c2;
        s3 += (double)a3; s3 += (double)c3;
        q0 += (double)a0 * (double)a0; q0 += (double)c0 * (double)c0;
        q1 += (double)a1 * (double)a1; q1 += (double)c1 * (double)c1;
        q2 += (double)a2 * (double)a2; q2 += (double)c2 * (double)c2;
        q3 += (double)a3 * (double)a3; q3 += (double)c3 * (double)c3;
    }
    __syncthreads();
    double* sS = (double*)smem;          // 64*17 doubles
    double* sQ = sS + 64 * 17;           // total 17408 B <= 24832 B
    sS[(cg * 4 + 0) * 17 + rr] = s0; sQ[(cg * 4 + 0) * 17 + rr] = q0;
    sS[(cg * 4 + 1) * 17 + rr] = s1; sQ[(cg * 4 + 1) * 17 + rr] = q1;
    sS[(cg * 4 + 2) * 17 + rr] = s2; sQ[(cg * 4 + 2) * 17 + rr] = q2;
    sS[(cg * 4 + 3) * 17 + rr] = s3; sQ[(cg * 4 + 3) * 17 + rr] = q3;
    __syncthreads();
    if (tid < 64) {
        double a = 0.0, b = 0.0;
#pragma unroll
        for (int r = 0; r < 16; r++) { a += sS[tid * 17 + r]; b += sQ[tid * 17 + r]; }
        part[(size_t)blockIdx.x * pstride + pbase + tid] = a;
        part[(size_t)blockIdx.x * pstride + pbase + 64 + tid] = b;
    }
}

// ------ fused: bitagg (into LDS) + dense GEMM + bias + stats, 2 tiles/block ------
// 512 threads = two half-blocks, each one 32-node tile; shared sW (16 KB) +
// 2x sx (8.3 KB) = 32.6 KB -> 4 blocks/CU x 8 waves = 32 waves/CU (cap).

__global__ __launch_bounds__(512, 8) void fusedL_k(const ulonglong2* __restrict__ pk,
                                                   const int* __restrict__ em,
                                                   int shift,
                                                   const int* __restrict__ rp,
                                                   const float* __restrict__ W,
                                                   const float* __restrict__ bias,
                                                   float* __restrict__ G,
                                                   double* __restrict__ part,
                                                   int pstride, int pbase) {
    __shared__ float smem[4096 + 2 * 2080];   // sW | sx[half0] | sx[half1]
    float* sW = smem;
    int tid = threadIdx.x;
    int h = tid >> 8;             // half 0/1
    int t8 = tid & 255;           // tid within half
    float* sx = smem + 4096 + h * 2080;
    int lane = tid & 63, w8 = t8 >> 6;
    const float4* W4 = (const float4*)W;
    float4* sW4 = (float4*)sW;
    for (int i = tid; i < 1024; i += 512) sW4[i] = W4[i];
    int sh31 = lane & 31;
    bool islo = lane < 32;
    int tile = blockIdx.x * 2 + h;
    bool valid = (tile < NTILE);
    if (valid) {
        for (int i = 0; i < 8; i++) {
            int n = tile * 32 + w8 * 8 + i;
            float acc = bitagg_nodeP(pk, em, shift, n, rp[n], rp[n + 1],
                                     lane, sh31, islo);
            sx[(w8 * 8 + i) * 65 + lane] = acc;
        }
    }
    __syncthreads();
    int cg = t8 & 15, rr = t8 >> 4;
    double s0 = 0, s1 = 0, s2 = 0, s3 = 0, q0 = 0, q1 = 0, q2 = 0, q3 = 0;
    if (valid) {
        float4 bv = *(const float4*)&bias[cg * 4];
        float a0 = bv.x, a1 = bv.y, a2 = bv.z, a3 = bv.w;
        float c0 = bv.x, c1 = bv.y, c2 = bv.z, c3 = bv.w;
#pragma unroll
        for (int k = 0; k < 64; k++) {
            float4 wv = *(const float4*)&sW[k * 64 + cg * 4];
            float xa = sx[rr * 65 + k];
            float xb = sx[(rr + 16) * 65 + k];
            a0 += xa * wv.x; a1 += xa * wv.y; a2 += xa * wv.z; a3 += xa * wv.w;
            c0 += xb * wv.x; c1 += xb * wv.y; c2 += xb * wv.z; c3 += xb * wv.w;
        }
        size_t r0 = (size_t)(tile * 32 + rr) * 64 + cg * 4;
        size_t r1 = (size_t)(tile * 32 + rr + 16) * 64 + cg * 4;
        *(float4*)&G[r0] = make_float4(a0, a1, a2, a3);
        *(float4*)&G[r1] = make_float4(c0, c1, c2, c3);
        s0 = (double)a0 + (double)c0;
        s1 = (double)a1 + (double)c1;
        s2 = (double)a2 + (double)c2;
        s3 = (double)a3 + (double)c3;
        q0 = (double)a0 * (double)a0 + (double)c0 * (double)c0;
        q1 = (double)a1 * (double)a1 + (double)c1 * (double)c1;
        q2 = (double)a2 * (double)a2 + (double)c2 * (double)c2;
        q3 = (double)a3 * (double)a3 + (double)c3 * (double)c3;
    }
    __syncthreads();
    double* sS = (double*)smem;          // 64*17 doubles (reuses dead sW/sx)
    double* sQ = sS + 64 * 17;
    if (h == 0) {
        sS[(cg * 4 + 0) * 17 + rr] = s0; sQ[(cg * 4 + 0) * 17 + rr] = q0;
        sS[(cg * 4 + 1) * 17 + rr] = s1; sQ[(cg * 4 + 1) * 17 + rr] = q1;
        sS[(cg * 4 + 2) * 17 + rr] = s2; sQ[(cg * 4 + 2) * 17 + rr] = q2;
        sS[(cg * 4 + 3) * 17 + rr] = s3; sQ[(cg * 4 + 3) * 17 + rr] = q3;
    }
    __syncthreads();
    if (h == 1) {
        sS[(cg * 4 + 0) * 17 + rr] += s0; sQ[(cg * 4 + 0) * 17 + rr] += q0;
        sS[(cg * 4 + 1) * 17 + rr] += s1; sQ[(cg * 4 + 1) * 17 + rr] += q1;
        sS[(cg * 4 + 2) * 17 + rr] += s2; sQ[(cg * 4 + 2) * 17 + rr] += q2;
        sS[(cg * 4 + 3) * 17 + rr] += s3; sQ[(cg * 4 + 3) * 17 + rr] += q3;
    }
    __syncthreads();
    if (tid < 64) {
        double a = 0.0, b = 0.0;
#pragma unroll
        for (int r = 0; r < 16; r++) { a += sS[tid * 17 + r]; b += sQ[tid * 17 + r]; }
        part[(size_t)blockIdx.x * pstride + pbase + tid] = a;
        part[(size_t)blockIdx.x * pstride + pbase + 64 + tid] = b;
    }
}

// ---------------- deterministic partial reduces ----------------

__global__ __launch_bounds__(256) void bn_red_k(const double* __restrict__ part,
                                                double* __restrict__ st,
                                                int rows) {
    __shared__ double tr[256];
    int t = threadIdx.x, c = blockIdx.x;
    double s = 0.0;
    for (int b = t; b < rows; b += 256) s += part[(size_t)b * 128 + c];
    tr[t] = s;
    __syncthreads();
    for (int off = 128; off > 0; off >>= 1) {
        if (t < off) tr[t] += tr[t + off];
        __syncthreads();
    }
    if (t == 0) st[c] = tr[0];
}

__global__ __launch_bounds__(256) void bn_red2_k(const double* __restrict__ part,
                                                 double* __restrict__ sta,
                                                 double* __restrict__ stb) {
    __shared__ double tr[256];
    int t = threadIdx.x, c = blockIdx.x;
    double s = 0.0;
    for (int b = t; b < NBE; b += 256) s += part[(size_t)b * 256 + c];
    tr[t] = s;
    __syncthreads();
    for (int off = 128; off > 0; off >>= 1) {
        if (t < off) tr[t] += tr[t + off];
        __syncthreads();
    }
    if (t == 0) {
        if (c < 128) sta[c] = tr[0];
        else stb[c - 128] = tr[0];
    }
}

__global__ __launch_bounds__(256) void bn_red3_k(const double* __restrict__ part,
                                                 double* __restrict__ sta,
                                                 double* __restrict__ stb,
                                                 double* __restrict__ stc) {
    __shared__ double tr[256];
    int t = threadIdx.x, c = blockIdx.x;
    double s = 0.0;
    for (int b = t; b < NBE; b += 256) s += part[(size_t)b * 384 + c];
    tr[t] = s;
    __syncthreads();
    for (int off = 128; off > 0; off >>= 1) {
        if (t < off) tr[t] += tr[t + off];
        __syncthreads();
    }
    if (t == 0) {
        if (c < 128) sta[c] = tr[0];
        else if (c < 256) stb[c - 128] = tr[0];
        else stc[c - 256] = tr[0];
    }
}

__device__ inline void bn_ss(const double* __restrict__ st, const float* __restrict__ gam,
                             const float* __restrict__ bet, int c,
                             float* __restrict__ ssc, float* __restrict__ ssh) {
    double m = st[c] * (1.0 / NN);
    double v = st[64 + c] * (1.0 / NN) - m * m;
    float scale = (float)((double)gam[c] / sqrt(v + (double)EPSF));
    ssc[c] = scale;
    ssh[c] = bet[c] - (float)m * scale;
}

// ---------------- spike-bit producer kernels (write bits to BOTH packed tables) ----

__global__ __launch_bounds__(256) void lif_spike_k(const float* __restrict__ G,
                                                   const double* __restrict__ st,
                                                   const float* __restrict__ gam,
                                                   const float* __restrict__ bet,
                                                   float* __restrict__ vconv,
                                                   u64* __restrict__ pkA,
                                                   u64* __restrict__ pkB) {
    __shared__ float ssc[64], ssh[64];
    int tid = threadIdx.x;
    if (tid < 64) bn_ss(st, gam, bet, tid, ssc, ssh);
    __syncthreads();
    int lane = tid & 63;
    size_t i = (size_t)blockIdx.x * 256 + tid;
    float v = vconv[i] + (G[i] * ssc[lane] + ssh[lane]);
    bool sp = (v - THF >= 0.0f);
    u64 m = __ballot(sp);
    vconv[i] = sp ? 0.0f : v;
    if (lane == 0) { pkA[(i >> 6) * 2] = m; pkB[(i >> 6) * 2] = m; }
}

__global__ __launch_bounds__(256) void spike_save_k(const float* __restrict__ G,
                                                    const double* __restrict__ st,
                                                    const float* __restrict__ gam,
                                                    const float* __restrict__ bet,
                                                    float* __restrict__ xsave,
                                                    u64* __restrict__ pkA,
                                                    u64* __restrict__ pkB) {
    __shared__ float ssc[64], ssh[64];
    int tid = threadIdx.x;
    if (tid < 64) bn_ss(st, gam, bet, tid, ssc, ssh);
    __syncthreads();
    int lane = tid & 63;
    size_t i = (size_t)blockIdx.x * 256 + tid;
    float xv = G[i] * ssc[lane] + ssh[lane];
    xsave[i] = xv;
    u64 m = __ballot(xv - THF >= 0.0f);
    if (lane == 0) { pkA[(i >> 6) * 2] = m; pkB[(i >> 6) * 2] = m; }
}

__global__ __launch_bounds__(256) void lif_spike_save_k(const float* __restrict__ F,
                                                        const double* __restrict__ st,
                                                        const float* __restrict__ gam,
                                                        const float* __restrict__ bet,
                                                        float* __restrict__ vconv,
                                                        float* __restrict__ xsave,
                                                        u64* __restrict__ pkA,
                                                        u64* __restrict__ pkB) {
    __shared__ float ssc[64], ssh[64];
    int tid = threadIdx.x;
    if (tid < 64) bn_ss(st, gam, bet, tid, ssc, ssh);
    __syncthreads();
    int lane = tid & 63;
    size_t i = (size_t)blockIdx.x * 256 + tid;
    float xv = F[i] * ssc[lane] + ssh[lane];
    xsave[i] = xv;
    float v = vconv[i] + xv;
    bool sp = (v - THF >= 0.0f);
    u64 m = __ballot(sp);
    vconv[i] = sp ? 0.0f : v;
    if (lane == 0) { pkA[(i >> 6) * 2] = m; pkB[(i >> 6) * 2] = m; }
}

__global__ __launch_bounds__(256) void qkv_att_spike_k(const float* __restrict__ Gq,
                                                       const float* __restrict__ Gk,
                                                       const float* __restrict__ Gv,
                                                       const double* __restrict__ st4,
                                                       const double* __restrict__ st5,
                                                       const double* __restrict__ st6,
                                                       const float* __restrict__ gam4,
                                                       const float* __restrict__ bet4,
                                                       const float* __restrict__ gam5,
                                                       const float* __restrict__ bet5,
                                                       const float* __restrict__ gam6,
                                                       const float* __restrict__ bet6,
                                                       u64* __restrict__ pkA,
                                                       u64* __restrict__ pkB) {
    __shared__ float sc4[64], sh4[64], sc5[64], sh5[64], sc6[64], sh6[64];
    int tid = threadIdx.x;
    if (tid < 64) {
        bn_ss(st4, gam4, bet4, tid, sc4, sh4);
        bn_ss(st5, gam5, bet5, tid, sc5, sh5);
        bn_ss(st6, gam6, bet6, tid, sc6, sh6);
    }
    __syncthreads();
    int lane = tid & 63;
    size_t i = (size_t)blockIdx.x * 256 + tid;
    bool qb = (Gq[i] * sc4[lane] + sh4[lane] - THF >= 0.0f);
    bool kb = (Gk[i] * sc5[lane] + sh5[lane] - THF >= 0.0f);
    bool vb = (Gv[i] * sc6[lane] + sh6[lane] - THF >= 0.0f);
    int pc = __popcll(__ballot(qb && kb));
    bool qs = ((float)pc * (1.0f / 64.0f) - ATTTH >= 0.0f);
    u64 m = __ballot(vb && qs);
    if (lane == 0) { pkA[(i >> 6) * 2] = m; pkB[(i >> 6) * 2] = m; }
}

// ---------------- remaining elementwise (with fused stats) ----------------

__global__ __launch_bounds__(256) void bn_add_stats_k(const float* __restrict__ G,
                                                      const double* __restrict__ st,
                                                      const float* __restrict__ gam,
                                                      const float* __restrict__ bet,
                                                      const float* __restrict__ x3,
                                                      float* __restrict__ F,
                                                      double* __restrict__ part) {
    __shared__ float ssc[64], ssh[64];
    int tid = threadIdx.x;
    if (tid < 64) bn_ss(st, gam, bet, tid, ssc, ssh);
    __syncthreads();
    int c = tid & 63;
    double s = 0.0, s2 = 0.0;
    for (size_t i = (size_t)blockIdx.x * 256 + tid; i < NHTOT; i += (size_t)NBE * 256) {
        float f = (G[i] * ssc[c] + ssh[c]) + x3[i];
        F[i] = f;
        s += (double)f;
        s2 += (double)f * (double)f;
    }
    __shared__ double ls[256], lq[256];
    ls[tid] = s; lq[tid] = s2;
    __syncthreads();
    if (tid < 64) {
        double a = ls[tid] + ls[tid + 64] + ls[tid + 128] + ls[tid + 192];
        double b = lq[tid] + lq[tid + 64] + lq[tid + 128] + lq[tid + 192];
        part[(size_t)blockIdx.x * 128 + tid] = a;
        part[(size_t)blockIdx.x * 128 + 64 + tid] = b;
    }
}

__global__ __launch_bounds__(256) void bn_scale_add_stats_k(const float* __restrict__ G,
                                                            const double* __restrict__ st,
                                                            const float* __restrict__ gam,
                                                            const float* __restrict__ bet,
                                                            const float* __restrict__ x4,
                                                            float* __restrict__ tmp2,
                                                            double* __restrict__ part) {
    __shared__ float ssc[64], ssh[64];
    int tid = threadIdx.x;
    if (tid < 64) bn_ss(st, gam, bet, tid, ssc, ssh);
    __syncthreads();
    int c = tid & 63;
    double s = 0.0, s2 = 0.0;
    for (size_t i = (size_t)blockIdx.x * 256 + tid; i < NHTOT; i += (size_t)NBE * 256) {
        float f = x4[i] + 0.125f * (G[i] * ssc[c] + ssh[c]);
        tmp2[i] = f;
        s += (double)f;
        s2 += (double)f * (double)f;
    }
    __shared__ double ls[256], lq[256];
    ls[tid] = s; lq[tid] = s2;
    __syncthreads();
    if (tid < 64) {
        double a = ls[tid] + ls[tid + 64] + ls[tid + 128] + ls[tid + 192];
        double b = lq[tid] + lq[tid + 64] + lq[tid + 128] + lq[tid + 192];
        part[(size_t)blockIdx.x * 128 + tid] = a;
        part[(size_t)blockIdx.x * 128 + 64 + tid] = b;
    }
}

__global__ __launch_bounds__(256) void decode_k(const float* __restrict__ tmp2,
                                                const double* __restrict__ st,
                                                const float* __restrict__ gam,
                                                const float* __restrict__ bet,
                                                const float* __restrict__ wrow,
                                                float* __restrict__ z) {
    __shared__ float ssc[64], ssh[64];
    int tid = threadIdx.x;
    if (tid < 64) bn_ss(st, gam, bet, tid, ssc, ssh);
    __syncthreads();
    int lane = tid & 63;
    int row = blockIdx.x * 4 + (tid >> 6);
    float sv = tmp2[(size_t)row * 64 + lane] * ssc[lane] + ssh[lane];
    float p = sv * wrow[lane];
#pragma unroll
    for (int off = 32; off > 0; off >>= 1) p += __shfl_xor(p, off, 64);
    if (lane == 0) z[row] = p;
}

__global__ void wrow_k(const float* __restrict__ W_lin, float* __restrict__ wrow) {
    int h = threadIdx.x;
    if (h >= 64) return;
    float s = 0.0f;
    for (int j = 0; j < 64; j++) s += W_lin[h * 64 + j];
    wrow[h] = s;
}

// ---------------- host driver ----------------

extern "C" void kernel_launch(void* const* d_in, const int* in_sizes, int n_in,
                              void* d_out, int out_size, void* d_ws, size_t ws_size,
                              hipStream_t stream) {
    const float* x    = (const float*)d_in[0];
    const int* eidx   = (const int*)d_in[1];
    const int* emask  = (const int*)d_in[2];
    const float* Wg   = (const float*)d_in[3];
    const float* bg   = (const float*)d_in[4];
    const float* bng  = (const float*)d_in[5];
    const float* bnb  = (const float*)d_in[6];
    const float* Wlin = (const float*)d_in[7];
    float* zout = (float*)d_out;

    const int* srcp = eidx;
    const int* dstp = eidx + NE;
    const size_t NH = (size_t)NN * HH;

    // ---- workspace layout ----
    float* ws = (float*)d_ws;
    size_t off = 0;
    float* P1 = ws + off; off += NH;
    float* P2 = ws + off; off += NH;
    float* P3 = ws + off; off += NH;
    float* P4 = ws + off; off += NH;
    float* P5 = ws + off; off += NH;
    float* vconv = ws + off; off += NH;
    int* emA = (int*)(ws + off); off += NE;
    int* emB = (int*)(ws + off); off += EM2CAP;
    float* pkAf = ws + off; off += (size_t)NN * 4;   // 16B records
    float* pkBf = ws + off; off += (size_t)NN * 4;
    float* dpk  = ws + off; off += (size_t)NN * 2;   // float2 records
    double* part = (double*)(ws + off); off += 2 * (size_t)NBE * 384;
    double* stats = (double*)(ws + off); off += 2 * 18 * 128;
    int* rk = (int*)(ws + off); off += NE;
    float* dis1 = ws + off; off += NN;
    float* d21  = ws + off; off += NN;
    float* dis2m = ws + off; off += NN;
    float* d22  = ws + off; off += NN;
    float* wrow = ws + off; off += 64;
    int* rp1 = (int*)(ws + off); off += NN + 2;
    int* rp2 = (int*)(ws + off); off += NN + 2;
    int* cntp = (int*)(ws + off); off += NN;
    int* bsum = (int*)(ws + off); off += 2 * SCAN_B + 4;
    if (off & 1) off++;
    float* P8 = ws + off; off += NH;
    size_t needA2 = off * 4;
    const bool tA2 = (ws_size >= needA2);

    const ulonglong2* pkA = (const ulonglong2*)pkAf;
    const ulonglong2* pkB = (const ulonglong2*)pkBf;
    u64* pkAu = (u64*)pkAf;
    u64* pkBu = (u64*)pkBf;

    hipMemsetAsync(cntp, 0, NN * sizeof(int), stream);
    hipMemsetAsync(vconv, 0, NH * sizeof(float), stream);

    const int NB_EDGE = NE / 256;
    const int NB_ROW4 = NN / 4;
    const int NB_GEMM = NN / 32;

    wrow_k<<<1, 64, 0, stream>>>(Wlin, wrow);
    hist_k<<<NB_EDGE, 256, 0, stream>>>(dstp, emask, cntp, rk);
    scan1d_k<<<2 * SCAN_B, 256, 0, stream>>>(cntp, rp1, rp2, bsum,
                                             dis1, d21, dis2m, d22,
                                             pkAf, pkBf, dpk);
    scan2d_k<<<1, 512, 0, stream>>>(bsum, rp1, rp2);
    scan3d_k<<<2 * SCAN_B, 256, 0, stream>>>(rp1, rp2, bsum);
    csr_fill_k<<<NB_EDGE, 256, 0, stream>>>(srcp, dstp, emask, rk, rp1, rp2,
                                            emA, emB);
    seg_sort2_k<<<2 * NB_ROW4C, 256, 0, stream>>>(emA, rp1, emB, rp2);

    auto enc = [&](const int* em, int shift, const ulonglong2* pk,
                   const float* dis, const int* rp,
                   const float* d2i, int bnbase, float* zo, const float* G0pre) {
        auto ST = [&](int bni) { return stats + (bnbase + bni) * 128; };
        auto W = [&](int wi) { return Wg + wi * 4096; };
        auto BI = [&](int wi) { return bg + wi * 64; };
        auto GM = [&](int bi) { return bng + bi * 64; };
        auto BT = [&](int bi) { return bnb + bi * 64; };

        const float* G0 = G0pre;
        if (!G0) {
            gemm_k<<<NB_GEMM, 256, 0, stream>>>(x, W(0), P1);
            gather_stats_k<<<NBE, 256, 0, stream>>>(P1, em, shift, dis, rp, d2i,
                                                    BI(0), P2, part);
            bn_red_k<<<128, 256, 0, stream>>>(part, ST(0), NBE);
            G0 = P2;
        }
        // conv_lif (stateful) -> spike bits
        lif_spike_k<<<NB_ROW4, 256, 0, stream>>>(G0, ST(0), GM(0), BT(0), vconv,
                                                 pkAu, pkBu);
        // layer 1: fused bitagg + GEMM + stats (2 tiles / 512-thread block)
        fusedL_k<<<NT2, 512, 0, stream>>>(pk, em, shift, rp,
                                          W(1), BI(1), P5, part, 128, 0);
        bn_red_k<<<128, 256, 0, stream>>>(part, ST(1), NT2);
        // pos branch spike (fresh LIF), keep x2 in P3
        spike_save_k<<<NB_ROW4, 256, 0, stream>>>(P5, ST(1), GM(1), BT(1), P3,
                                                  pkAu, pkBu);
        // layer 2
        fusedL_k<<<NT2, 512, 0, stream>>>(pk, em, shift, rp,
                                          W(2), BI(2), P5, part, 128, 0);
        bn_red_k<<<128, 256, 0, stream>>>(part, ST(2), NT2);
        // x4 = BN2(G2) + x2  (F in P4)
        bn_add_stats_k<<<NBE, 256, 0, stream>>>(P5, ST(2), GM(2), BT(2), P3, P4, part);
        bn_red_k<<<128, 256, 0, stream>>>(part, ST(3), NBE);
        // x5 = BN3(x4) saved in-place (P4); conv_lif second call -> bits
        lif_spike_save_k<<<NB_ROW4, 256, 0, stream>>>(P4, ST(3), GM(3), BT(3),
                                                      vconv, P4, pkAu, pkBu);
        // q/k/v: split path (full-occupancy bitagg + 3 dense GEMMs)
        bitagg_k<<<NBE, 256, 0, stream>>>(pk, em, shift, rp, P1);
        gemmb_stats_k<<<NBE, 256, 0, stream>>>(P1, W(3), BI(3), P2, part, 384, 0);
        gemmb_stats_k<<<NBE, 256, 0, stream>>>(P1, W(4), BI(4), P3, part, 384, 128);
        gemmb_stats_k<<<NBE, 256, 0, stream>>>(P1, W(5), BI(5), P5, part, 384, 256);
        bn_red3_k<<<384, 256, 0, stream>>>(part, ST(4), ST(5), ST(6));
        qkv_att_spike_k<<<NB_ROW4, 256, 0, stream>>>(P2, P3, P5,
                                                     ST(4), ST(5), ST(6),
                                                     GM(4), BT(4), GM(5), BT(5),
                                                     GM(6), BT(6), pkAu, pkBu);
        // att layer
        fusedL_k<<<NT2, 512, 0, stream>>>(pk, em, shift, rp,
                                          W(6), BI(6), P2, part, 128, 0);
        bn_red_k<<<128, 256, 0, stream>>>(part, ST(7), NT2);
        bn_scale_add_stats_k<<<NBE, 256, 0, stream>>>(P2, ST(7), GM(7), BT(7),
                                                      P4, P3, part);
        bn_red_k<<<128, 256, 0, stream>>>(part, ST(8), NBE);
        decode_k<<<NB_ROW4, 256, 0, stream>>>(P3, ST(8), GM(8), BT(8), wrow, zo);
    };

    if (tA2) {
        // shared L0 traversal: both encs' first (real-valued) aggregation in one pass
        gemm_k<<<NB_GEMM, 256, 0, stream>>>(x, Wg, P1);
        sharedL0_k<<<NBE, 256, 0, stream>>>(P1, emA, rp1, (const float2*)dpk,
                                            dis1, dis2m, d21, d22,
                                            bg, P2, P8, part);
        bn_red2_k<<<256, 256, 0, stream>>>(part, stats + 0 * 128, stats + 9 * 128);
        enc(emA, 1, pkA, dis1, rp1, d21, 0, zout, P2);
        enc(emB, 0, pkB, dis2m, rp2, d22, 9, zout + NN, P8);
    } else {
        enc(emA, 1, pkA, dis1, rp1, d21, 0, zout, nullptr);
        enc(emB, 0, pkB, dis2m, rp2, d22, 9, zout + NN, nullptr);
    }
}